// Round 1
// baseline (1211.074 us; speedup 1.0000x reference)
//
#include <hip/hip_runtime.h>

#define NN 50000          // nodes
#define NE 800000         // edges (without self loops)
#define NET 850000        // NE + NN self loops
#define NB_SCAN 49        // ceil(NN/1024)

__device__ __forceinline__ float bcast_lane(float v, int l) {
    return __int_as_float(__builtin_amdgcn_readlane(__float_as_int(v), l));
}
__device__ __forceinline__ float wred_max(float v) {
#pragma unroll
    for (int off = 32; off; off >>= 1) v = fmaxf(v, __shfl_xor(v, off, 64));
    return v;
}
__device__ __forceinline__ float wred_sum(float v) {
#pragma unroll
    for (int off = 32; off; off >>= 1) v += __shfl_xor(v, off, 64);
    return v;
}

// ---------------- CSR build ----------------
__global__ void k_count(const int* __restrict__ ei, int* __restrict__ cnt) {
    int e = blockIdx.x * blockDim.x + threadIdx.x;
    if (e < NET) {
        int i = (e < NE) ? ei[e] : (e - NE);   // self loop dest
        atomicAdd(&cnt[i], 1);
    }
}

__global__ __launch_bounds__(1024) void k_scan1(const int* __restrict__ cnt,
                                                int* __restrict__ rowptr,
                                                int* __restrict__ bsum) {
    __shared__ int sh[1024];
    int t = threadIdx.x;
    int i = blockIdx.x * 1024 + t;
    int v = (i < NN) ? cnt[i] : 0;
    sh[t] = v;
    __syncthreads();
    for (int off = 1; off < 1024; off <<= 1) {
        int add = (t >= off) ? sh[t - off] : 0;
        __syncthreads();
        sh[t] += add;
        __syncthreads();
    }
    int incl = sh[t];
    if (i < NN) rowptr[i] = incl - v;          // exclusive, pre-block-offset
    if (t == 1023) bsum[blockIdx.x] = incl;
}

__global__ void k_scan2(const int* __restrict__ bsum, int* __restrict__ boff,
                        int* __restrict__ rowptr) {
    int lane = threadIdx.x;                    // 64 threads, 1 block
    int v = (lane < NB_SCAN) ? bsum[lane] : 0;
    int p = v;
#pragma unroll
    for (int off = 1; off < 64; off <<= 1) {
        int nv = __shfl_up(p, off, 64);
        if (lane >= off) p += nv;
    }
    if (lane < NB_SCAN) boff[lane] = p - v;    // exclusive
    if (lane == 63) rowptr[NN] = p;            // grand total
}

__global__ __launch_bounds__(1024) void k_scan3(int* __restrict__ rowptr,
                                                const int* __restrict__ boff,
                                                int* __restrict__ cursor) {
    int i = blockIdx.x * 1024 + threadIdx.x;
    if (i < NN) {
        int r = rowptr[i] + boff[i >> 10];
        rowptr[i] = r;
        cursor[i] = r;
    }
}

__global__ void k_fill(const int* __restrict__ ei, const int* __restrict__ ej,
                       int* __restrict__ cursor, int* __restrict__ csrj) {
    int e = blockIdx.x * blockDim.x + threadIdx.x;
    if (e < NET) {
        int i, j;
        if (e < NE) { i = ei[e]; j = ej[e]; }
        else        { i = e - NE; j = i; }
        int pos = atomicAdd(&cursor[i], 1);
        csrj[pos] = j;
    }
}

// ---------------- opening: x0[n][o] = relu(K1 @ xn), plus s,d for layer 0 ----------------
__global__ __launch_bounds__(256) void k_open(const float* __restrict__ xn,
                                              const float* __restrict__ K1,
                                              const float* __restrict__ att_s,
                                              const float* __restrict__ att_d,
                                              float* __restrict__ x0,
                                              float* __restrict__ s0,
                                              float* __restrict__ d0) {
    __shared__ float xs[128][64];   // 32 KB  xs[c][local n]
    __shared__ float Kt[128][64];   // 32 KB  Kt[c][o] = K1[o][c]
    int t = threadIdx.x;
    int n0 = blockIdx.x * 64;

    for (int idx = t; idx < 128 * 64; idx += 256) {
        int c = idx >> 6, o = idx & 63;
        Kt[c][o] = K1[o * 128 + c];
    }
    for (int idx = t; idx < 128 * 64; idx += 256) {
        int c = idx >> 6, ln = idx & 63;
        int n = n0 + ln;
        xs[c][ln] = (n < NN) ? xn[(size_t)c * NN + n] : 0.f;
    }
    __syncthreads();

    int tx = t & 15;    // output quad: o = tx*4 .. tx*4+3
    int ty = t >> 4;    // node quad:   n = n0 + ty*4 .. +3

    float acc[4][4] = {};
    for (int c = 0; c < 128; ++c) {
        float4 xv = *(const float4*)&xs[c][ty * 4];
        float4 kv = *(const float4*)&Kt[c][tx * 4];
        acc[0][0] = fmaf(xv.x, kv.x, acc[0][0]); acc[0][1] = fmaf(xv.x, kv.y, acc[0][1]);
        acc[0][2] = fmaf(xv.x, kv.z, acc[0][2]); acc[0][3] = fmaf(xv.x, kv.w, acc[0][3]);
        acc[1][0] = fmaf(xv.y, kv.x, acc[1][0]); acc[1][1] = fmaf(xv.y, kv.y, acc[1][1]);
        acc[1][2] = fmaf(xv.y, kv.z, acc[1][2]); acc[1][3] = fmaf(xv.y, kv.w, acc[1][3]);
        acc[2][0] = fmaf(xv.z, kv.x, acc[2][0]); acc[2][1] = fmaf(xv.z, kv.y, acc[2][1]);
        acc[2][2] = fmaf(xv.z, kv.z, acc[2][2]); acc[2][3] = fmaf(xv.z, kv.w, acc[2][3]);
        acc[3][0] = fmaf(xv.w, kv.x, acc[3][0]); acc[3][1] = fmaf(xv.w, kv.y, acc[3][1]);
        acc[3][2] = fmaf(xv.w, kv.z, acc[3][2]); acc[3][3] = fmaf(xv.w, kv.w, acc[3][3]);
    }

    float asv[4], adv[4];
#pragma unroll
    for (int j = 0; j < 4; ++j) { asv[j] = att_s[tx * 4 + j]; adv[j] = att_d[tx * 4 + j]; }

#pragma unroll
    for (int i = 0; i < 4; ++i) {
        int n = n0 + ty * 4 + i;
        if (n >= NN) continue;                 // uniform across the 16-lane tx group
        float4 r;
        r.x = fmaxf(acc[i][0], 0.f); r.y = fmaxf(acc[i][1], 0.f);
        r.z = fmaxf(acc[i][2], 0.f); r.w = fmaxf(acc[i][3], 0.f);
        float ps = r.x * asv[0] + r.y * asv[1] + r.z * asv[2] + r.w * asv[3];
        float pd = r.x * adv[0] + r.y * adv[1] + r.z * adv[2] + r.w * adv[3];
#pragma unroll
        for (int off = 1; off < 16; off <<= 1) {
            ps += __shfl_xor(ps, off, 64);
            pd += __shfl_xor(pd, off, 64);
        }
        if (tx == 0) { s0[n] = ps; d0[n] = pd; }
        *(float4*)&x0[(size_t)n * 64 + tx * 4] = r;
    }
}

// ---------------- fused layer: attention softmax + SpMM + residual + 64x64 GEMM + relu ----------------
__global__ __launch_bounds__(256) void k_layer(const float* __restrict__ xin,
                                               float* __restrict__ xout,
                                               const float* __restrict__ sarr,
                                               const float* __restrict__ darr,
                                               float* __restrict__ snext,
                                               float* __restrict__ dnext,
                                               const int* __restrict__ rowptr,
                                               const int* __restrict__ csrj,
                                               const float* __restrict__ Kl,     // KN1 + l*4096, row-major [o][c]
                                               const float* __restrict__ om_l,   // omega + l*64
                                               const float* __restrict__ atts_n,
                                               const float* __restrict__ attd_n,
                                               int has_next) {
    int lane = threadIdx.x & 63;
    int n = (blockIdx.x * blockDim.x + threadIdx.x) >> 6;   // one wave per node
    if (n >= NN) return;

    // K row (o = lane) resident in registers
    float krow[64];
#pragma unroll
    for (int c = 0; c < 64; c += 4) {
        float4 kk = *(const float4*)&Kl[lane * 64 + c];
        krow[c] = kk.x; krow[c + 1] = kk.y; krow[c + 2] = kk.z; krow[c + 3] = kk.w;
    }

    int rs = rowptr[n], re = rowptr[n + 1];
    float s_n = sarr[n];

    // pass A: segment max, then exp-sum (lane-strided)
    float mx = -1e30f;
    for (int e = rs + lane; e < re; e += 64) {
        float a = s_n + darr[csrj[e]];
        a = (a > 0.f) ? a : 0.2f * a;
        mx = fmaxf(mx, a);
    }
    mx = wred_max(mx);
    float sm = 0.f;
    for (int e = rs + lane; e < re; e += 64) {
        float a = s_n + darr[csrj[e]];
        a = (a > 0.f) ? a : 0.2f * a;
        sm += __expf(a - mx);
    }
    sm = wred_sum(sm);
    float inv = 1.f / sm;

    // pass B: uniform edge loop, channel-per-lane gather-accumulate
    float acc = 0.f;
    for (int e = rs; e < re; ++e) {
        int j = csrj[e];
        float a = s_n + darr[j];
        a = (a > 0.f) ? a : 0.2f * a;
        float w = __expf(a - mx);
        acc = fmaf(w, xin[(size_t)j * 64 + lane], acc);
    }
    acc *= inv;

    // omega residual
    float xc = xin[(size_t)n * 64 + lane];
    float om = om_l[lane];
    float tmp = xc - om * (xc - acc);

    // 64x64 GEMM: y[lane] = sum_c K[lane][c] * tmp[c]
    float y = 0.f;
#pragma unroll
    for (int c = 0; c < 64; ++c) {
        y = fmaf(krow[c], bcast_lane(tmp, c), y);
    }
    y = fmaxf(y, 0.f);
    xout[(size_t)n * 64 + lane] = y;

    if (has_next) {
        float ps = wred_sum(atts_n[lane] * y);
        float pd = wred_sum(attd_n[lane] * y);
        if (lane == 0) { snext[n] = ps; dnext[n] = pd; }
    }
}

// ---------------- closing: z = KNclose @ x ; out = log_softmax(z) ----------------
__global__ __launch_bounds__(256) void k_close(const float* __restrict__ xin,
                                               const float* __restrict__ KNc,  // [40][64]
                                               float* __restrict__ out) {
    int lane = threadIdx.x & 63;
    int n = (blockIdx.x * blockDim.x + threadIdx.x) >> 6;
    if (n >= NN) return;

    float krow[64];
#pragma unroll
    for (int c = 0; c < 64; ++c) krow[c] = (lane < 40) ? KNc[lane * 64 + c] : 0.f;

    float xv = xin[(size_t)n * 64 + lane];
    float z = 0.f;
#pragma unroll
    for (int c = 0; c < 64; ++c) {
        z = fmaf(krow[c], bcast_lane(xv, c), z);
    }

    float zm = (lane < 40) ? z : -1e30f;
    float m = wred_max(zm);
    float p = (lane < 40) ? __expf(z - m) : 0.f;
    float sum = wred_sum(p);
    float res = z - m - logf(sum);
    if (lane < 40) out[(size_t)n * 40 + lane] = res;
}

// ---------------- host ----------------
extern "C" void kernel_launch(void* const* d_in, const int* in_sizes, int n_in,
                              void* d_out, int out_size, void* d_ws, size_t ws_size,
                              hipStream_t stream) {
    const float* xn    = (const float*)d_in[0];
    const float* K1    = (const float*)d_in[1];
    const float* KNc   = (const float*)d_in[2];
    const float* KN1   = (const float*)d_in[3];
    const float* atts  = (const float*)d_in[4];
    const float* attd  = (const float*)d_in[5];
    const float* omega = (const float*)d_in[6];
    const int*   ei    = (const int*)d_in[7];
    const int*   ej    = (const int*)d_in[8];
    float* out = (float*)d_out;

    char* ws = (char*)d_ws;
    size_t off = 0;
    auto alloc = [&](size_t b) -> void* {
        void* p = ws + off;
        off = (off + b + 255) & ~(size_t)255;
        return p;
    };
    float* xa     = (float*)alloc((size_t)NN * 64 * 4);
    float* xb     = (float*)alloc((size_t)NN * 64 * 4);
    float* sA     = (float*)alloc((size_t)NN * 4);
    float* dA     = (float*)alloc((size_t)NN * 4);
    float* sB     = (float*)alloc((size_t)NN * 4);
    float* dB     = (float*)alloc((size_t)NN * 4);
    int*   rowptr = (int*)alloc((size_t)(NN + 1) * 4);
    int*   cursor = (int*)alloc((size_t)NN * 4);
    int*   csrj   = (int*)alloc((size_t)NET * 4);
    int*   bsum   = (int*)alloc((size_t)NB_SCAN * 4);
    int*   boff   = (int*)alloc((size_t)NB_SCAN * 4);
    if (off > ws_size) return;   // workspace too small: fail loudly via validation

    // CSR build (once per call; I is fixed across layers)
    hipMemsetAsync(cursor, 0, (size_t)NN * 4, stream);
    k_count<<<(NET + 255) / 256, 256, 0, stream>>>(ei, cursor);
    k_scan1<<<NB_SCAN, 1024, 0, stream>>>(cursor, rowptr, bsum);
    k_scan2<<<1, 64, 0, stream>>>(bsum, boff, rowptr);
    k_scan3<<<NB_SCAN, 1024, 0, stream>>>(rowptr, boff, cursor);
    k_fill<<<(NET + 255) / 256, 256, 0, stream>>>(ei, ej, cursor, csrj);

    // opening
    k_open<<<(NN + 63) / 64, 256, 0, stream>>>(xn, K1, atts, attd, xa, sA, dA);

    // layers (ping-pong x and s/d)
    const float* xi = xa; float* xo = xb;
    const float* si = sA; const float* di = dA;
    float* so = sB; float* dn = dB;
    for (int l = 0; l < 4; ++l) {
        int hn = (l < 3) ? 1 : 0;
        int nl = (l < 3) ? (l + 1) : 0;
        k_layer<<<12500, 256, 0, stream>>>(xi, xo, si, di, so, dn, rowptr, csrj,
                                           KN1 + (size_t)l * 4096, omega + l * 64,
                                           atts + (size_t)nl * 64, attd + (size_t)nl * 64, hn);
        const float* t0 = xi; xi = xo; xo = (float*)t0;
        const float* t1 = si; si = so; so = (float*)t1;
        const float* t2 = di; di = dn; dn = (float*)t2;
    }

    // closing + log_softmax
    k_close<<<12500, 256, 0, stream>>>(xi, KNc, out);
}

// Round 2
// 491.555 us; speedup vs baseline: 2.4638x; 2.4638x over previous
//
#include <hip/hip_runtime.h>

#define NN 50000          // nodes
#define NE 800000         // edges (without self loops)
#define NET 850000        // NE + NN self loops
#define NB_SCAN 49        // ceil(NN/1024)
#define NPW 8             // nodes per wave in k_layer / k_close

__device__ __forceinline__ float bcast_lane(float v, int l) {
    return __int_as_float(__builtin_amdgcn_readlane(__float_as_int(v), l));
}
__device__ __forceinline__ float wred_max(float v) {
#pragma unroll
    for (int off = 32; off; off >>= 1) v = fmaxf(v, __shfl_xor(v, off, 64));
    return v;
}
__device__ __forceinline__ float wred_sum(float v) {
#pragma unroll
    for (int off = 32; off; off >>= 1) v += __shfl_xor(v, off, 64);
    return v;
}

// ---------------- CSR build ----------------
__global__ void k_count(const int* __restrict__ ei, int* __restrict__ cnt) {
    int e = blockIdx.x * blockDim.x + threadIdx.x;
    if (e < NET) {
        int i = (e < NE) ? ei[e] : (e - NE);   // self loop dest
        atomicAdd(&cnt[i], 1);
    }
}

__global__ __launch_bounds__(1024) void k_scan1(const int* __restrict__ cnt,
                                                int* __restrict__ rowptr,
                                                int* __restrict__ bsum) {
    __shared__ int sh[1024];
    int t = threadIdx.x;
    int i = blockIdx.x * 1024 + t;
    int v = (i < NN) ? cnt[i] : 0;
    sh[t] = v;
    __syncthreads();
    for (int off = 1; off < 1024; off <<= 1) {
        int add = (t >= off) ? sh[t - off] : 0;
        __syncthreads();
        sh[t] += add;
        __syncthreads();
    }
    int incl = sh[t];
    if (i < NN) rowptr[i] = incl - v;          // exclusive, pre-block-offset
    if (t == 1023) bsum[blockIdx.x] = incl;
}

__global__ void k_scan2(const int* __restrict__ bsum, int* __restrict__ boff,
                        int* __restrict__ rowptr) {
    int lane = threadIdx.x;                    // 64 threads, 1 block
    int v = (lane < NB_SCAN) ? bsum[lane] : 0;
    int p = v;
#pragma unroll
    for (int off = 1; off < 64; off <<= 1) {
        int nv = __shfl_up(p, off, 64);
        if (lane >= off) p += nv;
    }
    if (lane < NB_SCAN) boff[lane] = p - v;    // exclusive
    if (lane == 63) rowptr[NN] = p;            // grand total
}

__global__ __launch_bounds__(1024) void k_scan3(int* __restrict__ rowptr,
                                                const int* __restrict__ boff,
                                                int* __restrict__ cursor) {
    int i = blockIdx.x * 1024 + threadIdx.x;
    if (i < NN) {
        int r = rowptr[i] + boff[i >> 10];
        rowptr[i] = r;
        cursor[i] = r;
    }
}

__global__ void k_fill(const int* __restrict__ ei, const int* __restrict__ ej,
                       int* __restrict__ cursor, int* __restrict__ csrj) {
    int e = blockIdx.x * blockDim.x + threadIdx.x;
    if (e < NET) {
        int i, j;
        if (e < NE) { i = ei[e]; j = ej[e]; }
        else        { i = e - NE; j = i; }
        int pos = atomicAdd(&cursor[i], 1);
        csrj[pos] = j;
    }
}

// ---------------- opening: x0[n][o] = relu(K1 @ xn), plus s,d for layer 0 ----------------
__global__ __launch_bounds__(256) void k_open(const float* __restrict__ xn,
                                              const float* __restrict__ K1,
                                              const float* __restrict__ att_s,
                                              const float* __restrict__ att_d,
                                              float* __restrict__ x0,
                                              float* __restrict__ s0,
                                              float* __restrict__ d0) {
    __shared__ float xs[128][64];   // 32 KB  xs[c][local n]
    __shared__ float Kt[128][64];   // 32 KB  Kt[c][o] = K1[o][c]
    int t = threadIdx.x;
    int n0 = blockIdx.x * 64;

    for (int idx = t; idx < 128 * 64; idx += 256) {
        int c = idx >> 6, o = idx & 63;
        Kt[c][o] = K1[o * 128 + c];
    }
    for (int idx = t; idx < 128 * 64; idx += 256) {
        int c = idx >> 6, ln = idx & 63;
        int n = n0 + ln;
        xs[c][ln] = (n < NN) ? xn[(size_t)c * NN + n] : 0.f;
    }
    __syncthreads();

    int tx = t & 15;    // output quad: o = tx*4 .. tx*4+3
    int ty = t >> 4;    // node quad:   n = n0 + ty*4 .. +3

    float acc[4][4] = {};
    for (int c = 0; c < 128; ++c) {
        float4 xv = *(const float4*)&xs[c][ty * 4];
        float4 kv = *(const float4*)&Kt[c][tx * 4];
        acc[0][0] = fmaf(xv.x, kv.x, acc[0][0]); acc[0][1] = fmaf(xv.x, kv.y, acc[0][1]);
        acc[0][2] = fmaf(xv.x, kv.z, acc[0][2]); acc[0][3] = fmaf(xv.x, kv.w, acc[0][3]);
        acc[1][0] = fmaf(xv.y, kv.x, acc[1][0]); acc[1][1] = fmaf(xv.y, kv.y, acc[1][1]);
        acc[1][2] = fmaf(xv.y, kv.z, acc[1][2]); acc[1][3] = fmaf(xv.y, kv.w, acc[1][3]);
        acc[2][0] = fmaf(xv.z, kv.x, acc[2][0]); acc[2][1] = fmaf(xv.z, kv.y, acc[2][1]);
        acc[2][2] = fmaf(xv.z, kv.z, acc[2][2]); acc[2][3] = fmaf(xv.z, kv.w, acc[2][3]);
        acc[3][0] = fmaf(xv.w, kv.x, acc[3][0]); acc[3][1] = fmaf(xv.w, kv.y, acc[3][1]);
        acc[3][2] = fmaf(xv.w, kv.z, acc[3][2]); acc[3][3] = fmaf(xv.w, kv.w, acc[3][3]);
    }

    float asv[4], adv[4];
#pragma unroll
    for (int j = 0; j < 4; ++j) { asv[j] = att_s[tx * 4 + j]; adv[j] = att_d[tx * 4 + j]; }

#pragma unroll
    for (int i = 0; i < 4; ++i) {
        int n = n0 + ty * 4 + i;
        if (n >= NN) continue;                 // uniform across the 16-lane tx group
        float4 r;
        r.x = fmaxf(acc[i][0], 0.f); r.y = fmaxf(acc[i][1], 0.f);
        r.z = fmaxf(acc[i][2], 0.f); r.w = fmaxf(acc[i][3], 0.f);
        float ps = r.x * asv[0] + r.y * asv[1] + r.z * asv[2] + r.w * asv[3];
        float pd = r.x * adv[0] + r.y * adv[1] + r.z * adv[2] + r.w * adv[3];
#pragma unroll
        for (int off = 1; off < 16; off <<= 1) {
            ps += __shfl_xor(ps, off, 64);
            pd += __shfl_xor(pd, off, 64);
        }
        if (tx == 0) { s0[n] = ps; d0[n] = pd; }
        *(float4*)&x0[(size_t)n * 64 + tx * 4] = r;
    }
}

// ---------------- fused layer: attention softmax + SpMM + residual + 64x64 GEMM + relu ----------------
// K staged in LDS (padded, conflict-free); 8 nodes per wave; register-cached edge
// list with shfl broadcast + 4-way unrolled gather for latency overlap.
__global__ __launch_bounds__(256) void k_layer(const float* __restrict__ xin,
                                               float* __restrict__ xout,
                                               const float* __restrict__ sarr,
                                               const float* __restrict__ darr,
                                               float* __restrict__ snext,
                                               float* __restrict__ dnext,
                                               const int* __restrict__ rowptr,
                                               const int* __restrict__ csrj,
                                               const float* __restrict__ Kl,     // [64][64] row-major
                                               const float* __restrict__ om_l,
                                               const float* __restrict__ atts_n,
                                               const float* __restrict__ attd_n,
                                               int has_next) {
    __shared__ float Kpad[64][65];             // +1 pad: bank = (row+c)%32, conflict-free
    int t = threadIdx.x;
    for (int idx = t; idx < 64 * 64; idx += 256)
        Kpad[idx >> 6][idx & 63] = Kl[idx];    // coalesced global read
    __syncthreads();

    int lane = t & 63;
    int wid = t >> 6;

    float krow[64];
#pragma unroll
    for (int c = 0; c < 64; ++c) krow[c] = Kpad[lane][c];  // conflict-free LDS

    float om = om_l[lane];
    float as_ = atts_n[lane];
    float ad_ = attd_n[lane];

    int nbase = (blockIdx.x * 4 + wid) * NPW;
    for (int k = 0; k < NPW; ++k) {
        int n = nbase + k;
        if (n >= NN) break;                    // wave-uniform
        int rs = rowptr[n], re = rowptr[n + 1];
        int deg = re - rs;
        float s_n = sarr[n];
        float mx, inv;
        float acc = 0.f;

        if (deg <= 64) {
            // lane-strided edge cache (one edge per lane)
            int jl = (lane < deg) ? csrj[rs + lane] : 0;
            float dl = (lane < deg) ? darr[jl] : -1e30f;
            // leaky_relu monotone: max_e LR(s+d_j) = LR(s + max_e d_j)
            float mxd = wred_max(dl);
            float aa = s_n + mxd;
            mx = (aa > 0.f) ? aa : 0.2f * aa;
            float al = s_n + dl;
            al = (al > 0.f) ? al : 0.2f * al;
            float wl = (lane < deg) ? __expf(al - mx) : 0.f;
            float sm = wred_sum(wl);
            inv = 1.f / sm;

            // 4-way unrolled gather (independent loads in flight)
            int tt = 0;
            for (; tt + 4 <= deg; tt += 4) {
                int j0 = __shfl(jl, tt);     float w0 = __shfl(wl, tt);
                int j1 = __shfl(jl, tt + 1); float w1 = __shfl(wl, tt + 1);
                int j2 = __shfl(jl, tt + 2); float w2 = __shfl(wl, tt + 2);
                int j3 = __shfl(jl, tt + 3); float w3 = __shfl(wl, tt + 3);
                float x0v = xin[(size_t)j0 * 64 + lane];
                float x1v = xin[(size_t)j1 * 64 + lane];
                float x2v = xin[(size_t)j2 * 64 + lane];
                float x3v = xin[(size_t)j3 * 64 + lane];
                acc = fmaf(w0, x0v, acc);
                acc = fmaf(w1, x1v, acc);
                acc = fmaf(w2, x2v, acc);
                acc = fmaf(w3, x3v, acc);
            }
            for (; tt < deg; ++tt) {
                int j0 = __shfl(jl, tt);
                float w0 = __shfl(wl, tt);
                acc = fmaf(w0, xin[(size_t)j0 * 64 + lane], acc);
            }
            acc *= inv;
        } else {
            // generic fallback (deg > 64: astronomically rare, kept for correctness)
            float mxd = -1e30f;
            for (int e = rs + lane; e < re; e += 64) mxd = fmaxf(mxd, darr[csrj[e]]);
            mxd = wred_max(mxd);
            float aa = s_n + mxd;
            mx = (aa > 0.f) ? aa : 0.2f * aa;
            float sm = 0.f;
            for (int e = rs + lane; e < re; e += 64) {
                float a = s_n + darr[csrj[e]];
                a = (a > 0.f) ? a : 0.2f * a;
                sm += __expf(a - mx);
            }
            sm = wred_sum(sm);
            inv = 1.f / sm;
            for (int e = rs; e < re; ++e) {
                int j = csrj[e];
                float a = s_n + darr[j];
                a = (a > 0.f) ? a : 0.2f * a;
                acc = fmaf(__expf(a - mx), xin[(size_t)j * 64 + lane], acc);
            }
            acc *= inv;
        }

        // omega residual
        float xc = xin[(size_t)n * 64 + lane];
        float tmp = xc - om * (xc - acc);

        // 64x64 GEMM: y[lane=o] = sum_c K[o][c] * tmp[c]
        float y = 0.f;
#pragma unroll
        for (int c = 0; c < 64; ++c)
            y = fmaf(krow[c], bcast_lane(tmp, c), y);
        y = fmaxf(y, 0.f);
        xout[(size_t)n * 64 + lane] = y;

        if (has_next) {
            float ps = wred_sum(as_ * y);
            float pd = wred_sum(ad_ * y);
            if (lane == 0) { snext[n] = ps; dnext[n] = pd; }
        }
    }
}

// ---------------- closing: z = KNclose @ x ; out = log_softmax(z) ----------------
__global__ __launch_bounds__(256) void k_close(const float* __restrict__ xin,
                                               const float* __restrict__ KNc,  // [40][64]
                                               float* __restrict__ out) {
    __shared__ float Kpad[40][65];
    int t = threadIdx.x;
    for (int idx = t; idx < 40 * 64; idx += 256)
        Kpad[idx >> 6][idx & 63] = KNc[idx];   // coalesced global read
    __syncthreads();

    int lane = t & 63;
    int wid = t >> 6;

    float krow[64];
#pragma unroll
    for (int c = 0; c < 64; ++c) krow[c] = (lane < 40) ? Kpad[(lane < 40) ? lane : 0][c] : 0.f;

    int nbase = (blockIdx.x * 4 + wid) * NPW;
    for (int k = 0; k < NPW; ++k) {
        int n = nbase + k;
        if (n >= NN) break;                    // wave-uniform

        float xv = xin[(size_t)n * 64 + lane];
        float z = 0.f;
#pragma unroll
        for (int c = 0; c < 64; ++c)
            z = fmaf(krow[c], bcast_lane(xv, c), z);

        float zm = (lane < 40) ? z : -1e30f;
        float m = wred_max(zm);
        float p = (lane < 40) ? __expf(z - m) : 0.f;
        float sum = wred_sum(p);
        float res = z - m - logf(sum);
        if (lane < 40) out[(size_t)n * 40 + lane] = res;
    }
}

// ---------------- host ----------------
extern "C" void kernel_launch(void* const* d_in, const int* in_sizes, int n_in,
                              void* d_out, int out_size, void* d_ws, size_t ws_size,
                              hipStream_t stream) {
    const float* xn    = (const float*)d_in[0];
    const float* K1    = (const float*)d_in[1];
    const float* KNc   = (const float*)d_in[2];
    const float* KN1   = (const float*)d_in[3];
    const float* atts  = (const float*)d_in[4];
    const float* attd  = (const float*)d_in[5];
    const float* omega = (const float*)d_in[6];
    const int*   ei    = (const int*)d_in[7];
    const int*   ej    = (const int*)d_in[8];
    float* out = (float*)d_out;

    char* ws = (char*)d_ws;
    size_t off = 0;
    auto alloc = [&](size_t b) -> void* {
        void* p = ws + off;
        off = (off + b + 255) & ~(size_t)255;
        return p;
    };
    float* xa     = (float*)alloc((size_t)NN * 64 * 4);
    float* xb     = (float*)alloc((size_t)NN * 64 * 4);
    float* sA     = (float*)alloc((size_t)NN * 4);
    float* dA     = (float*)alloc((size_t)NN * 4);
    float* sB     = (float*)alloc((size_t)NN * 4);
    float* dB     = (float*)alloc((size_t)NN * 4);
    int*   rowptr = (int*)alloc((size_t)(NN + 1) * 4);
    int*   cursor = (int*)alloc((size_t)NN * 4);
    int*   csrj   = (int*)alloc((size_t)NET * 4);
    int*   bsum   = (int*)alloc((size_t)NB_SCAN * 4);
    int*   boff   = (int*)alloc((size_t)NB_SCAN * 4);
    if (off > ws_size) return;

    // CSR build (once per call; I is fixed across layers)
    hipMemsetAsync(cursor, 0, (size_t)NN * 4, stream);
    k_count<<<(NET + 255) / 256, 256, 0, stream>>>(ei, cursor);
    k_scan1<<<NB_SCAN, 1024, 0, stream>>>(cursor, rowptr, bsum);
    k_scan2<<<1, 64, 0, stream>>>(bsum, boff, rowptr);
    k_scan3<<<NB_SCAN, 1024, 0, stream>>>(rowptr, boff, cursor);
    k_fill<<<(NET + 255) / 256, 256, 0, stream>>>(ei, ej, cursor, csrj);

    // opening
    k_open<<<(NN + 63) / 64, 256, 0, stream>>>(xn, K1, atts, attd, xa, sA, dA);

    // layers (ping-pong x and s/d)
    const int LBLK = (NN + 4 * NPW - 1) / (4 * NPW);   // 1563
    const float* xi = xa; float* xo = xb;
    const float* si = sA; const float* di = dA;
    float* so = sB; float* dn = dB;
    for (int l = 0; l < 4; ++l) {
        int hn = (l < 3) ? 1 : 0;
        int nl = (l < 3) ? (l + 1) : 0;
        k_layer<<<LBLK, 256, 0, stream>>>(xi, xo, si, di, so, dn, rowptr, csrj,
                                          KN1 + (size_t)l * 4096, omega + l * 64,
                                          atts + (size_t)nl * 64, attd + (size_t)nl * 64, hn);
        const float* t0 = xi; xi = xo; xo = (float*)t0;
        const float* t1 = si; si = so; so = (float*)t1;
        const float* t2 = di; di = dn; dn = (float*)t2;
    }

    // closing + log_softmax
    k_close<<<LBLK, 256, 0, stream>>>(xi, KNc, out);
}

// Round 4
// 479.745 us; speedup vs baseline: 2.5244x; 1.0246x over previous
//
#include <hip/hip_runtime.h>

#define NN 50000          // nodes
#define NE 800000         // edges (without self loops)
#define NET 850000        // NE + NN self loops
#define NB_SCAN 49        // ceil(NN/1024)
#define NPW 8             // nodes per wave in k_layer / k_close

typedef unsigned int uint;
typedef unsigned short ushort;

__device__ __forceinline__ float bcast_lane(float v, int l) {
    return __int_as_float(__builtin_amdgcn_readlane(__float_as_int(v), l));
}
__device__ __forceinline__ float wred_max(float v) {
#pragma unroll
    for (int off = 32; off; off >>= 1) v = fmaxf(v, __shfl_xor(v, off, 64));
    return v;
}
__device__ __forceinline__ float wred_sum(float v) {
#pragma unroll
    for (int off = 32; off; off >>= 1) v += __shfl_xor(v, off, 64);
    return v;
}
__device__ __forceinline__ ushort f2bf(float f) {   // RNE
    uint u = __float_as_uint(f);
    return (ushort)((u + 0x7fffu + ((u >> 16) & 1u)) >> 16);
}
__device__ __forceinline__ float bflo(uint u) { return __uint_as_float(u << 16); }
__device__ __forceinline__ float bfhi(uint u) { return __uint_as_float(u & 0xffff0000u); }

__device__ __forceinline__ void acc8_fma(float* acc8, float wgt, uint4 v) {
    acc8[0] = fmaf(wgt, bflo(v.x), acc8[0]);
    acc8[1] = fmaf(wgt, bfhi(v.x), acc8[1]);
    acc8[2] = fmaf(wgt, bflo(v.y), acc8[2]);
    acc8[3] = fmaf(wgt, bfhi(v.y), acc8[3]);
    acc8[4] = fmaf(wgt, bflo(v.z), acc8[4]);
    acc8[5] = fmaf(wgt, bfhi(v.z), acc8[5]);
    acc8[6] = fmaf(wgt, bflo(v.w), acc8[6]);
    acc8[7] = fmaf(wgt, bfhi(v.w), acc8[7]);
}

// ---------------- CSR build ----------------
__global__ void k_count(const int* __restrict__ ei, int* __restrict__ cnt) {
    int e = blockIdx.x * blockDim.x + threadIdx.x;
    if (e < NET) {
        int i = (e < NE) ? ei[e] : (e - NE);   // self loop dest
        atomicAdd(&cnt[i], 1);
    }
}

__global__ __launch_bounds__(1024) void k_scan1(const int* __restrict__ cnt,
                                                int* __restrict__ rowptr,
                                                int* __restrict__ bsum) {
    __shared__ int sh[1024];
    int t = threadIdx.x;
    int i = blockIdx.x * 1024 + t;
    int v = (i < NN) ? cnt[i] : 0;
    sh[t] = v;
    __syncthreads();
    for (int off = 1; off < 1024; off <<= 1) {
        int add = (t >= off) ? sh[t - off] : 0;
        __syncthreads();
        sh[t] += add;
        __syncthreads();
    }
    int incl = sh[t];
    if (i < NN) rowptr[i] = incl - v;          // exclusive, pre-block-offset
    if (t == 1023) bsum[blockIdx.x] = incl;
}

__global__ void k_scan2(const int* __restrict__ bsum, int* __restrict__ boff,
                        int* __restrict__ rowptr) {
    int lane = threadIdx.x;                    // 64 threads, 1 block
    int v = (lane < NB_SCAN) ? bsum[lane] : 0;
    int p = v;
#pragma unroll
    for (int off = 1; off < 64; off <<= 1) {
        int nv = __shfl_up(p, off, 64);
        if (lane >= off) p += nv;
    }
    if (lane < NB_SCAN) boff[lane] = p - v;    // exclusive
    if (lane == 63) rowptr[NN] = p;            // grand total
}

__global__ __launch_bounds__(1024) void k_scan3(int* __restrict__ rowptr,
                                                const int* __restrict__ boff,
                                                int* __restrict__ cursor) {
    int i = blockIdx.x * 1024 + threadIdx.x;
    if (i < NN) {
        int r = rowptr[i] + boff[i >> 10];
        rowptr[i] = r;
        cursor[i] = r;
    }
}

__global__ void k_fill(const int* __restrict__ ei, const int* __restrict__ ej,
                       int* __restrict__ cursor, int* __restrict__ csrj) {
    int e = blockIdx.x * blockDim.x + threadIdx.x;
    if (e < NET) {
        int i, j;
        if (e < NE) { i = ei[e]; j = ej[e]; }
        else        { i = e - NE; j = i; }
        int pos = atomicAdd(&cursor[i], 1);
        csrj[pos] = j;
    }
}

// ---------------- opening: x0[n][o] = relu(K1 @ xn) (bf16 out), plus s,d ----------------
__global__ __launch_bounds__(256) void k_open(const float* __restrict__ xn,
                                              const float* __restrict__ K1,
                                              const float* __restrict__ att_s,
                                              const float* __restrict__ att_d,
                                              ushort* __restrict__ x0,
                                              float* __restrict__ s0,
                                              float* __restrict__ d0) {
    __shared__ float xs[128][64];   // 32 KB  xs[c][local n]
    __shared__ float Kt[128][64];   // 32 KB  Kt[c][o] = K1[o][c]
    int t = threadIdx.x;
    int n0 = blockIdx.x * 64;

    for (int idx = t; idx < 128 * 64; idx += 256) {
        int c = idx >> 6, o = idx & 63;
        Kt[c][o] = K1[o * 128 + c];
    }
    for (int idx = t; idx < 128 * 64; idx += 256) {
        int c = idx >> 6, ln = idx & 63;
        int n = n0 + ln;
        xs[c][ln] = (n < NN) ? xn[(size_t)c * NN + n] : 0.f;
    }
    __syncthreads();

    int tx = t & 15;    // output quad: o = tx*4 .. tx*4+3
    int ty = t >> 4;    // node quad:   n = n0 + ty*4 .. +3

    float acc[4][4] = {};
    for (int c = 0; c < 128; ++c) {
        float4 xv = *(const float4*)&xs[c][ty * 4];
        float4 kv = *(const float4*)&Kt[c][tx * 4];
        acc[0][0] = fmaf(xv.x, kv.x, acc[0][0]); acc[0][1] = fmaf(xv.x, kv.y, acc[0][1]);
        acc[0][2] = fmaf(xv.x, kv.z, acc[0][2]); acc[0][3] = fmaf(xv.x, kv.w, acc[0][3]);
        acc[1][0] = fmaf(xv.y, kv.x, acc[1][0]); acc[1][1] = fmaf(xv.y, kv.y, acc[1][1]);
        acc[1][2] = fmaf(xv.y, kv.z, acc[1][2]); acc[1][3] = fmaf(xv.y, kv.w, acc[1][3]);
        acc[2][0] = fmaf(xv.z, kv.x, acc[2][0]); acc[2][1] = fmaf(xv.z, kv.y, acc[2][1]);
        acc[2][2] = fmaf(xv.z, kv.z, acc[2][2]); acc[2][3] = fmaf(xv.z, kv.w, acc[2][3]);
        acc[3][0] = fmaf(xv.w, kv.x, acc[3][0]); acc[3][1] = fmaf(xv.w, kv.y, acc[3][1]);
        acc[3][2] = fmaf(xv.w, kv.z, acc[3][2]); acc[3][3] = fmaf(xv.w, kv.w, acc[3][3]);
    }

    float asv[4], adv[4];
#pragma unroll
    for (int j = 0; j < 4; ++j) { asv[j] = att_s[tx * 4 + j]; adv[j] = att_d[tx * 4 + j]; }

#pragma unroll
    for (int i = 0; i < 4; ++i) {
        int n = n0 + ty * 4 + i;
        if (n >= NN) continue;                 // uniform across the 16-lane tx group
        float4 r;
        r.x = fmaxf(acc[i][0], 0.f); r.y = fmaxf(acc[i][1], 0.f);
        r.z = fmaxf(acc[i][2], 0.f); r.w = fmaxf(acc[i][3], 0.f);
        float ps = r.x * asv[0] + r.y * asv[1] + r.z * asv[2] + r.w * asv[3];
        float pd = r.x * adv[0] + r.y * adv[1] + r.z * adv[2] + r.w * adv[3];
#pragma unroll
        for (int off = 1; off < 16; off <<= 1) {
            ps += __shfl_xor(ps, off, 64);
            pd += __shfl_xor(pd, off, 64);
        }
        if (tx == 0) { s0[n] = ps; d0[n] = pd; }
        ushort4 h;
        h.x = f2bf(r.x); h.y = f2bf(r.y); h.z = f2bf(r.z); h.w = f2bf(r.w);
        *(ushort4*)&x0[(size_t)n * 64 + tx * 4] = h;
    }
}

// ---------------- fused layer ----------------
// bf16 x storage; 16B/lane gathers cover 8 edges per load instruction
// (lane = 8*edge_group + channel_octet); softmax/accum/GEMM in fp32.
__global__ __launch_bounds__(256) void k_layer(const ushort* __restrict__ xin,
                                               ushort* __restrict__ xout,
                                               const float* __restrict__ sarr,
                                               const float* __restrict__ darr,
                                               float* __restrict__ snext,
                                               float* __restrict__ dnext,
                                               const int* __restrict__ rowptr,
                                               const int* __restrict__ csrj,
                                               const float* __restrict__ Kl,     // [64][64] row-major
                                               const float* __restrict__ om_l,
                                               const float* __restrict__ atts_n,
                                               const float* __restrict__ attd_n,
                                               int has_next) {
    __shared__ float Kpad[64][65];             // +1 pad: conflict-free
    int t = threadIdx.x;
    for (int idx = t; idx < 64 * 64; idx += 256)
        Kpad[idx >> 6][idx & 63] = Kl[idx];    // coalesced global read
    __syncthreads();

    int lane = t & 63;
    int wid = t >> 6;
    int g  = lane >> 3;   // edge subgroup 0..7
    int c8 = lane & 7;    // channel octet: channels c8*8 .. c8*8+7

    float krow[64];
#pragma unroll
    for (int c = 0; c < 64; ++c) krow[c] = Kpad[lane][c];

    float om8[8];
    {
        float4 a = *(const float4*)&om_l[c8 * 8];
        float4 b = *(const float4*)&om_l[c8 * 8 + 4];
        om8[0] = a.x; om8[1] = a.y; om8[2] = a.z; om8[3] = a.w;
        om8[4] = b.x; om8[5] = b.y; om8[6] = b.z; om8[7] = b.w;
    }
    float as_ = atts_n[lane];
    float ad_ = attd_n[lane];

    int nbase = (blockIdx.x * 4 + wid) * NPW;
    for (int k = 0; k < NPW; ++k) {
        int n = nbase + k;
        if (n >= NN) break;                    // wave-uniform
        int rs = rowptr[n], re = rowptr[n + 1];
        int deg = re - rs;
        float s_n = sarr[n];
        float inv;
        float acc8[8] = {0.f, 0.f, 0.f, 0.f, 0.f, 0.f, 0.f, 0.f};

        if (deg <= 64) {
            // lane-strided edge cache (one edge per lane)
            int   jl = (lane < deg) ? csrj[rs + lane] : 0;
            float dl = (lane < deg) ? darr[jl] : -1e30f;
            // leaky_relu monotone: max_e LR(s+d_j) = LR(s + max_e d_j)
            float mxd = wred_max(dl);
            float aa = s_n + mxd;
            float mx = (aa > 0.f) ? aa : 0.2f * aa;
            float al = s_n + dl;
            al = (al > 0.f) ? al : 0.2f * al;
            float wl = (lane < deg) ? __expf(al - mx) : 0.f;
            inv = 1.f / wred_sum(wl);

            // gather: 8 edges per uint4 load, 2x unroll => 16 edges in flight
            int tt = 0;
            for (; tt + 16 <= deg; tt += 16) {
                int e0 = tt + g, e1 = tt + 8 + g;
                int   j0 = __shfl(jl, e0); float w0 = __shfl(wl, e0);
                int   j1 = __shfl(jl, e1); float w1 = __shfl(wl, e1);
                uint4 v0 = *(const uint4*)(xin + (((size_t)j0) << 6) + (c8 << 3));
                uint4 v1 = *(const uint4*)(xin + (((size_t)j1) << 6) + (c8 << 3));
                acc8_fma(acc8, w0, v0);
                acc8_fma(acc8, w1, v1);
            }
            for (; tt < deg; tt += 8) {
                int e = tt + g;
                bool ok = e < deg;
                int ec = ok ? e : 0;
                int   j = __shfl(jl, ec);
                float w = ok ? __shfl(wl, ec) : 0.f;
                uint4 v = *(const uint4*)(xin + (((size_t)j) << 6) + (c8 << 3));
                acc8_fma(acc8, w, v);
            }
            // reduce across the 8 edge groups
#pragma unroll
            for (int q = 0; q < 8; ++q) {
                float v = acc8[q];
                v += __shfl_xor(v, 8, 64);
                v += __shfl_xor(v, 16, 64);
                v += __shfl_xor(v, 32, 64);
                acc8[q] = v;
            }
        } else {
            // generic fallback (deg > 64: astronomically rare)
            float mxd = -1e30f;
            for (int e = rs + lane; e < re; e += 64) mxd = fmaxf(mxd, darr[csrj[e]]);
            mxd = wred_max(mxd);
            float aa = s_n + mxd;
            float mx = (aa > 0.f) ? aa : 0.2f * aa;
            float sm = 0.f;
            for (int e = rs + lane; e < re; e += 64) {
                float a = s_n + darr[csrj[e]];
                a = (a > 0.f) ? a : 0.2f * a;
                sm += __expf(a - mx);
            }
            sm = wred_sum(sm);
            inv = 1.f / sm;
            for (int e = rs; e < re; ++e) {
                int j = csrj[e];
                float a = s_n + darr[j];
                a = (a > 0.f) ? a : 0.2f * a;
                float w = __expf(a - mx);
                uint4 v = *(const uint4*)(xin + (((size_t)j) << 6) + (c8 << 3));
                acc8_fma(acc8, w, v);
            }
        }

        // omega residual in octet layout
        uint4 xcv = *(const uint4*)(xin + (((size_t)n) << 6) + (c8 << 3));
        float xc[8];
        xc[0] = bflo(xcv.x); xc[1] = bfhi(xcv.x);
        xc[2] = bflo(xcv.y); xc[3] = bfhi(xcv.y);
        xc[4] = bflo(xcv.z); xc[5] = bfhi(xcv.z);
        xc[6] = bflo(xcv.w); xc[7] = bfhi(xcv.w);
        float tmp8[8];
#pragma unroll
        for (int q = 0; q < 8; ++q) {
            float a = acc8[q] * inv;
            tmp8[q] = xc[q] - om8[q] * (xc[q] - a);
        }

        // 64x64 GEMM: y[o=lane] = sum_c K[o][c] * tmp[c]; tmp[8q+k] lives on lane q
        float y = 0.f;
#pragma unroll
        for (int q = 0; q < 8; ++q) {
#pragma unroll
            for (int kk = 0; kk < 8; ++kk)
                y = fmaf(krow[q * 8 + kk], bcast_lane(tmp8[kk], q), y);
        }
        y = fmaxf(y, 0.f);
        xout[(size_t)n * 64 + lane] = f2bf(y);

        if (has_next) {
            float ps = wred_sum(as_ * y);
            float pd = wred_sum(ad_ * y);
            if (lane == 0) { snext[n] = ps; dnext[n] = pd; }
        }
    }
}

// ---------------- closing: z = KNclose @ x ; out = log_softmax(z) ----------------
__global__ __launch_bounds__(256) void k_close(const ushort* __restrict__ xin,
                                               const float* __restrict__ KNc,  // [40][64]
                                               float* __restrict__ out) {
    __shared__ float Kpad[40][65];
    int t = threadIdx.x;
    for (int idx = t; idx < 40 * 64; idx += 256)
        Kpad[idx >> 6][idx & 63] = KNc[idx];   // coalesced global read
    __syncthreads();

    int lane = t & 63;
    int wid = t >> 6;

    float krow[64];
    int kr = (lane < 40) ? lane : 0;
#pragma unroll
    for (int c = 0; c < 64; ++c) krow[c] = (lane < 40) ? Kpad[kr][c] : 0.f;

    int nbase = (blockIdx.x * 4 + wid) * NPW;
    for (int k = 0; k < NPW; ++k) {
        int n = nbase + k;
        if (n >= NN) break;                    // wave-uniform

        float xv = bflo((uint)xin[(size_t)n * 64 + lane]);
        float z = 0.f;
#pragma unroll
        for (int c = 0; c < 64; ++c)
            z = fmaf(krow[c], bcast_lane(xv, c), z);

        float zm = (lane < 40) ? z : -1e30f;
        float m = wred_max(zm);
        float p = (lane < 40) ? __expf(z - m) : 0.f;
        float sum = wred_sum(p);
        float res = z - m - logf(sum);
        if (lane < 40) out[(size_t)n * 40 + lane] = res;
    }
}

// ---------------- host ----------------
extern "C" void kernel_launch(void* const* d_in, const int* in_sizes, int n_in,
                              void* d_out, int out_size, void* d_ws, size_t ws_size,
                              hipStream_t stream) {
    const float* xn    = (const float*)d_in[0];
    const float* K1    = (const float*)d_in[1];
    const float* KNc   = (const float*)d_in[2];
    const float* KN1   = (const float*)d_in[3];
    const float* atts  = (const float*)d_in[4];
    const float* attd  = (const float*)d_in[5];
    const float* omega = (const float*)d_in[6];
    const int*   ei    = (const int*)d_in[7];
    const int*   ej    = (const int*)d_in[8];
    float* out = (float*)d_out;

    char* ws = (char*)d_ws;
    size_t off = 0;
    auto alloc = [&](size_t b) -> void* {
        void* p = ws + off;
        off = (off + b + 255) & ~(size_t)255;
        return p;
    };
    ushort* xa    = (ushort*)alloc((size_t)NN * 64 * 2);
    ushort* xb    = (ushort*)alloc((size_t)NN * 64 * 2);
    float* sA     = (float*)alloc((size_t)NN * 4);
    float* dA     = (float*)alloc((size_t)NN * 4);
    float* sB     = (float*)alloc((size_t)NN * 4);
    float* dB     = (float*)alloc((size_t)NN * 4);
    int*   rowptr = (int*)alloc((size_t)(NN + 1) * 4);
    int*   cursor = (int*)alloc((size_t)NN * 4);
    int*   csrj   = (int*)alloc((size_t)NET * 4);
    int*   bsum   = (int*)alloc((size_t)NB_SCAN * 4);
    int*   boff   = (int*)alloc((size_t)NB_SCAN * 4);
    if (off > ws_size) return;

    // CSR build (once per call; I is fixed across layers)
    (void)hipMemsetAsync(cursor, 0, (size_t)NN * 4, stream);
    k_count<<<(NET + 255) / 256, 256, 0, stream>>>(ei, cursor);
    k_scan1<<<NB_SCAN, 1024, 0, stream>>>(cursor, rowptr, bsum);
    k_scan2<<<1, 64, 0, stream>>>(bsum, boff, rowptr);
    k_scan3<<<NB_SCAN, 1024, 0, stream>>>(rowptr, boff, cursor);
    k_fill<<<(NET + 255) / 256, 256, 0, stream>>>(ei, ej, cursor, csrj);

    // opening
    k_open<<<(NN + 63) / 64, 256, 0, stream>>>(xn, K1, atts, attd, xa, sA, dA);

    // layers (ping-pong x and s/d)
    const int LBLK = (NN + 4 * NPW - 1) / (4 * NPW);   // 1563
    const ushort* xi = xa; ushort* xo = xb;
    const float* si = sA; const float* di = dA;
    float* so = sB; float* dn = dB;
    for (int l = 0; l < 4; ++l) {
        int hn = (l < 3) ? 1 : 0;
        int nl = (l < 3) ? (l + 1) : 0;
        k_layer<<<LBLK, 256, 0, stream>>>(xi, xo, si, di, so, dn, rowptr, csrj,
                                          KN1 + (size_t)l * 4096, omega + l * 64,
                                          atts + (size_t)nl * 64, attd + (size_t)nl * 64, hn);
        const ushort* t0 = xi; xi = xo; xo = (ushort*)t0;
        const float* t1 = si; si = so; so = (float*)t1;
        const float* t2 = di; di = dn; dn = (float*)t2;
    }

    // closing + log_softmax
    k_close<<<LBLK, 256, 0, stream>>>(xi, KNc, out);
}

// Round 5
// 460.648 us; speedup vs baseline: 2.6291x; 1.0415x over previous
//
#include <hip/hip_runtime.h>

#define NN 50000          // nodes
#define NE 800000         // edges (without self loops)
#define NET 850000        // NE + NN self loops
#define NB_SCAN 49        // ceil(NN/1024)
#define NPW 2             // nodes per wave in k_layer / k_close (R5: 8->2 for wave count)

typedef unsigned int uint;
typedef unsigned short ushort;

__device__ __forceinline__ float bcast_lane(float v, int l) {
    return __int_as_float(__builtin_amdgcn_readlane(__float_as_int(v), l));
}
__device__ __forceinline__ float wred_max(float v) {
#pragma unroll
    for (int off = 32; off; off >>= 1) v = fmaxf(v, __shfl_xor(v, off, 64));
    return v;
}
__device__ __forceinline__ float wred_sum(float v) {
#pragma unroll
    for (int off = 32; off; off >>= 1) v += __shfl_xor(v, off, 64);
    return v;
}
__device__ __forceinline__ ushort f2bf(float f) {   // RNE
    uint u = __float_as_uint(f);
    return (ushort)((u + 0x7fffu + ((u >> 16) & 1u)) >> 16);
}
__device__ __forceinline__ float bflo(uint u) { return __uint_as_float(u << 16); }
__device__ __forceinline__ float bfhi(uint u) { return __uint_as_float(u & 0xffff0000u); }

__device__ __forceinline__ void acc8_fma(float* acc8, float wgt, uint4 v) {
    acc8[0] = fmaf(wgt, bflo(v.x), acc8[0]);
    acc8[1] = fmaf(wgt, bfhi(v.x), acc8[1]);
    acc8[2] = fmaf(wgt, bflo(v.y), acc8[2]);
    acc8[3] = fmaf(wgt, bfhi(v.y), acc8[3]);
    acc8[4] = fmaf(wgt, bflo(v.z), acc8[4]);
    acc8[5] = fmaf(wgt, bfhi(v.z), acc8[5]);
    acc8[6] = fmaf(wgt, bflo(v.w), acc8[6]);
    acc8[7] = fmaf(wgt, bfhi(v.w), acc8[7]);
}

// Aggregate one node: softmax over incoming edges + weighted gather.
// Writes NORMALIZED per-octet sums (replicated across the 8 edge groups).
__device__ __forceinline__ void node_aggregate(const ushort* __restrict__ xin,
                                               const float* __restrict__ darr,
                                               const int* __restrict__ csrj,
                                               int rs, int deg, float s_n,
                                               int jl, float dl,
                                               int lane, int g, int c8,
                                               float* out8) {
    float acc8[8] = {0.f, 0.f, 0.f, 0.f, 0.f, 0.f, 0.f, 0.f};
    float inv;
    if (deg <= 64) {
        // leaky_relu monotone: max_e LR(s+d_j) = LR(s + max_e d_j)
        float mxd = wred_max(dl);
        float aa = s_n + mxd;
        float mx = (aa > 0.f) ? aa : 0.2f * aa;
        float al = s_n + dl;
        al = (al > 0.f) ? al : 0.2f * al;
        float wl = (lane < deg) ? __expf(al - mx) : 0.f;
        inv = 1.f / wred_sum(wl);

        // gather: 8 edges per uint4 load, 2x unroll => 16 edges in flight
        int tt = 0;
        for (; tt + 16 <= deg; tt += 16) {
            int e0 = tt + g, e1 = tt + 8 + g;
            int   j0 = __shfl(jl, e0); float w0 = __shfl(wl, e0);
            int   j1 = __shfl(jl, e1); float w1 = __shfl(wl, e1);
            uint4 v0 = *(const uint4*)(xin + (((size_t)j0) << 6) + (c8 << 3));
            uint4 v1 = *(const uint4*)(xin + (((size_t)j1) << 6) + (c8 << 3));
            acc8_fma(acc8, w0, v0);
            acc8_fma(acc8, w1, v1);
        }
        for (; tt < deg; tt += 8) {
            int e = tt + g;
            bool ok = e < deg;
            int ec = ok ? e : 0;
            int   j = __shfl(jl, ec);
            float w = ok ? __shfl(wl, ec) : 0.f;
            uint4 v = *(const uint4*)(xin + (((size_t)j) << 6) + (c8 << 3));
            acc8_fma(acc8, w, v);
        }
        // reduce across the 8 edge groups
#pragma unroll
        for (int q = 0; q < 8; ++q) {
            float v = acc8[q];
            v += __shfl_xor(v, 8, 64);
            v += __shfl_xor(v, 16, 64);
            v += __shfl_xor(v, 32, 64);
            acc8[q] = v;
        }
    } else {
        // generic fallback (deg > 64: astronomically rare)
        int re = rs + deg;
        float mxd = -1e30f;
        for (int e = rs + lane; e < re; e += 64) mxd = fmaxf(mxd, darr[csrj[e]]);
        mxd = wred_max(mxd);
        float aa = s_n + mxd;
        float mx = (aa > 0.f) ? aa : 0.2f * aa;
        float sm = 0.f;
        for (int e = rs + lane; e < re; e += 64) {
            float a = s_n + darr[csrj[e]];
            a = (a > 0.f) ? a : 0.2f * a;
            sm += __expf(a - mx);
        }
        sm = wred_sum(sm);
        inv = 1.f / sm;
        for (int e = rs; e < re; ++e) {
            int j = csrj[e];
            float a = s_n + darr[j];
            a = (a > 0.f) ? a : 0.2f * a;
            float w = __expf(a - mx);
            uint4 v = *(const uint4*)(xin + (((size_t)j) << 6) + (c8 << 3));
            acc8_fma(acc8, w, v);
        }
    }
#pragma unroll
    for (int q = 0; q < 8; ++q) out8[q] = acc8[q] * inv;
}

// ---------------- CSR build ----------------
__global__ void k_count(const int* __restrict__ ei, int* __restrict__ cnt) {
    int e = blockIdx.x * blockDim.x + threadIdx.x;
    if (e < NET) {
        int i = (e < NE) ? ei[e] : (e - NE);   // self loop dest
        atomicAdd(&cnt[i], 1);
    }
}

__global__ __launch_bounds__(1024) void k_scan1(const int* __restrict__ cnt,
                                                int* __restrict__ rowptr,
                                                int* __restrict__ bsum) {
    __shared__ int sh[1024];
    int t = threadIdx.x;
    int i = blockIdx.x * 1024 + t;
    int v = (i < NN) ? cnt[i] : 0;
    sh[t] = v;
    __syncthreads();
    for (int off = 1; off < 1024; off <<= 1) {
        int add = (t >= off) ? sh[t - off] : 0;
        __syncthreads();
        sh[t] += add;
        __syncthreads();
    }
    int incl = sh[t];
    if (i < NN) rowptr[i] = incl - v;          // exclusive, pre-block-offset
    if (t == 1023) bsum[blockIdx.x] = incl;
}

__global__ void k_scan2(const int* __restrict__ bsum, int* __restrict__ boff,
                        int* __restrict__ rowptr) {
    int lane = threadIdx.x;                    // 64 threads, 1 block
    int v = (lane < NB_SCAN) ? bsum[lane] : 0;
    int p = v;
#pragma unroll
    for (int off = 1; off < 64; off <<= 1) {
        int nv = __shfl_up(p, off, 64);
        if (lane >= off) p += nv;
    }
    if (lane < NB_SCAN) boff[lane] = p - v;    // exclusive
    if (lane == 63) rowptr[NN] = p;            // grand total
}

__global__ __launch_bounds__(1024) void k_scan3(int* __restrict__ rowptr,
                                                const int* __restrict__ boff,
                                                int* __restrict__ cursor) {
    int i = blockIdx.x * 1024 + threadIdx.x;
    if (i < NN) {
        int r = rowptr[i] + boff[i >> 10];
        rowptr[i] = r;
        cursor[i] = r;
    }
}

__global__ void k_fill(const int* __restrict__ ei, const int* __restrict__ ej,
                       int* __restrict__ cursor, int* __restrict__ csrj) {
    int e = blockIdx.x * blockDim.x + threadIdx.x;
    if (e < NET) {
        int i, j;
        if (e < NE) { i = ei[e]; j = ej[e]; }
        else        { i = e - NE; j = i; }
        int pos = atomicAdd(&cursor[i], 1);
        csrj[pos] = j;
    }
}

// ---------------- opening: x0[n][o] = relu(K1 @ xn) (bf16 out), plus s,d ----------------
__global__ __launch_bounds__(256) void k_open(const float* __restrict__ xn,
                                              const float* __restrict__ K1,
                                              const float* __restrict__ att_s,
                                              const float* __restrict__ att_d,
                                              ushort* __restrict__ x0,
                                              float* __restrict__ s0,
                                              float* __restrict__ d0) {
    __shared__ float xs[128][64];   // 32 KB  xs[c][local n]
    __shared__ float Kt[128][64];   // 32 KB  Kt[c][o] = K1[o][c]
    int t = threadIdx.x;
    int n0 = blockIdx.x * 64;

    for (int idx = t; idx < 128 * 64; idx += 256) {
        int c = idx >> 6, o = idx & 63;
        Kt[c][o] = K1[o * 128 + c];
    }
    for (int idx = t; idx < 128 * 64; idx += 256) {
        int c = idx >> 6, ln = idx & 63;
        int n = n0 + ln;
        xs[c][ln] = (n < NN) ? xn[(size_t)c * NN + n] : 0.f;
    }
    __syncthreads();

    int tx = t & 15;    // output quad: o = tx*4 .. tx*4+3
    int ty = t >> 4;    // node quad:   n = n0 + ty*4 .. +3

    float acc[4][4] = {};
    for (int c = 0; c < 128; ++c) {
        float4 xv = *(const float4*)&xs[c][ty * 4];
        float4 kv = *(const float4*)&Kt[c][tx * 4];
        acc[0][0] = fmaf(xv.x, kv.x, acc[0][0]); acc[0][1] = fmaf(xv.x, kv.y, acc[0][1]);
        acc[0][2] = fmaf(xv.x, kv.z, acc[0][2]); acc[0][3] = fmaf(xv.x, kv.w, acc[0][3]);
        acc[1][0] = fmaf(xv.y, kv.x, acc[1][0]); acc[1][1] = fmaf(xv.y, kv.y, acc[1][1]);
        acc[1][2] = fmaf(xv.y, kv.z, acc[1][2]); acc[1][3] = fmaf(xv.y, kv.w, acc[1][3]);
        acc[2][0] = fmaf(xv.z, kv.x, acc[2][0]); acc[2][1] = fmaf(xv.z, kv.y, acc[2][1]);
        acc[2][2] = fmaf(xv.z, kv.z, acc[2][2]); acc[2][3] = fmaf(xv.z, kv.w, acc[2][3]);
        acc[3][0] = fmaf(xv.w, kv.x, acc[3][0]); acc[3][1] = fmaf(xv.w, kv.y, acc[3][1]);
        acc[3][2] = fmaf(xv.w, kv.z, acc[3][2]); acc[3][3] = fmaf(xv.w, kv.w, acc[3][3]);
    }

    float asv[4], adv[4];
#pragma unroll
    for (int j = 0; j < 4; ++j) { asv[j] = att_s[tx * 4 + j]; adv[j] = att_d[tx * 4 + j]; }

#pragma unroll
    for (int i = 0; i < 4; ++i) {
        int n = n0 + ty * 4 + i;
        if (n >= NN) continue;                 // uniform across the 16-lane tx group
        float4 r;
        r.x = fmaxf(acc[i][0], 0.f); r.y = fmaxf(acc[i][1], 0.f);
        r.z = fmaxf(acc[i][2], 0.f); r.w = fmaxf(acc[i][3], 0.f);
        float ps = r.x * asv[0] + r.y * asv[1] + r.z * asv[2] + r.w * asv[3];
        float pd = r.x * adv[0] + r.y * adv[1] + r.z * adv[2] + r.w * adv[3];
#pragma unroll
        for (int off = 1; off < 16; off <<= 1) {
            ps += __shfl_xor(ps, off, 64);
            pd += __shfl_xor(pd, off, 64);
        }
        if (tx == 0) { s0[n] = ps; d0[n] = pd; }
        ushort4 h;
        h.x = f2bf(r.x); h.y = f2bf(r.y); h.z = f2bf(r.z); h.w = f2bf(r.w);
        *(ushort4*)&x0[(size_t)n * 64 + tx * 4] = h;
    }
}

// ---------------- fused layer ----------------
// NPW=2: two nodes per wave, processed with maximal cross-node ILP:
// headers/edge caches/x-center rows loaded up front, fused dual GEMM.
__global__ __launch_bounds__(256) void k_layer(const ushort* __restrict__ xin,
                                               ushort* __restrict__ xout,
                                               const float* __restrict__ sarr,
                                               const float* __restrict__ darr,
                                               float* __restrict__ snext,
                                               float* __restrict__ dnext,
                                               const int* __restrict__ rowptr,
                                               const int* __restrict__ csrj,
                                               const float* __restrict__ Kl,     // [64][64] row-major
                                               const float* __restrict__ om_l,
                                               const float* __restrict__ atts_n,
                                               const float* __restrict__ attd_n,
                                               int has_next) {
    __shared__ float Kpad[64][65];             // +1 pad: conflict-free
    int t = threadIdx.x;
    for (int idx = t; idx < 64 * 64; idx += 256)
        Kpad[idx >> 6][idx & 63] = Kl[idx];    // coalesced global read
    __syncthreads();

    int lane = t & 63;
    int wid = t >> 6;
    int g  = lane >> 3;   // edge subgroup 0..7
    int c8 = lane & 7;    // channel octet: channels c8*8 .. c8*8+7

    float krow[64];
#pragma unroll
    for (int c = 0; c < 64; ++c) krow[c] = Kpad[lane][c];

    int n0 = (blockIdx.x * 4 + wid) * NPW;     // grid exact: n0+1 < NN always

    // ---- prologue: both nodes' headers + edge caches + center rows (max MLP) ----
    int r0 = rowptr[n0], r1 = rowptr[n0 + 1], r2 = rowptr[n0 + 2];
    int deg0 = r1 - r0, deg1 = r2 - r1;
    float sn0 = sarr[n0], sn1 = sarr[n0 + 1];
    int   jl0 = (lane < deg0) ? csrj[r0 + lane] : 0;
    int   jl1 = (lane < deg1) ? csrj[r1 + lane] : 0;
    float dl0 = (lane < deg0) ? darr[jl0] : -1e30f;
    float dl1 = (lane < deg1) ? darr[jl1] : -1e30f;
    uint4 xcv0 = *(const uint4*)(xin + (((size_t)n0) << 6) + (c8 << 3));
    uint4 xcv1 = *(const uint4*)(xin + (((size_t)(n0 + 1)) << 6) + (c8 << 3));

    // ---- aggregate both nodes ----
    float t0a[8], t1a[8];
    node_aggregate(xin, darr, csrj, r0, deg0, sn0, jl0, dl0, lane, g, c8, t0a);
    node_aggregate(xin, darr, csrj, r1, deg1, sn1, jl1, dl1, lane, g, c8, t1a);

    // ---- omega residual (in place) ----
    {
        float4 a = *(const float4*)&om_l[c8 * 8];
        float4 b = *(const float4*)&om_l[c8 * 8 + 4];
        float om8[8] = {a.x, a.y, a.z, a.w, b.x, b.y, b.z, b.w};
        float xc;
        xc = bflo(xcv0.x); t0a[0] = xc - om8[0] * (xc - t0a[0]);
        xc = bfhi(xcv0.x); t0a[1] = xc - om8[1] * (xc - t0a[1]);
        xc = bflo(xcv0.y); t0a[2] = xc - om8[2] * (xc - t0a[2]);
        xc = bfhi(xcv0.y); t0a[3] = xc - om8[3] * (xc - t0a[3]);
        xc = bflo(xcv0.z); t0a[4] = xc - om8[4] * (xc - t0a[4]);
        xc = bfhi(xcv0.z); t0a[5] = xc - om8[5] * (xc - t0a[5]);
        xc = bflo(xcv0.w); t0a[6] = xc - om8[6] * (xc - t0a[6]);
        xc = bfhi(xcv0.w); t0a[7] = xc - om8[7] * (xc - t0a[7]);
        xc = bflo(xcv1.x); t1a[0] = xc - om8[0] * (xc - t1a[0]);
        xc = bfhi(xcv1.x); t1a[1] = xc - om8[1] * (xc - t1a[1]);
        xc = bflo(xcv1.y); t1a[2] = xc - om8[2] * (xc - t1a[2]);
        xc = bfhi(xcv1.y); t1a[3] = xc - om8[3] * (xc - t1a[3]);
        xc = bflo(xcv1.z); t1a[4] = xc - om8[4] * (xc - t1a[4]);
        xc = bfhi(xcv1.z); t1a[5] = xc - om8[5] * (xc - t1a[5]);
        xc = bflo(xcv1.w); t1a[6] = xc - om8[6] * (xc - t1a[6]);
        xc = bfhi(xcv1.w); t1a[7] = xc - om8[7] * (xc - t1a[7]);
    }

    // ---- fused dual 64x64 GEMM: 4 independent FMA chains ----
    float y0a = 0.f, y0b = 0.f, y1a = 0.f, y1b = 0.f;
#pragma unroll
    for (int q = 0; q < 8; ++q) {
#pragma unroll
        for (int kk = 0; kk < 8; kk += 2) {
            float k0 = krow[q * 8 + kk];
            float k1 = krow[q * 8 + kk + 1];
            float b0 = bcast_lane(t0a[kk], q);
            float b1 = bcast_lane(t0a[kk + 1], q);
            float c0 = bcast_lane(t1a[kk], q);
            float c1 = bcast_lane(t1a[kk + 1], q);
            y0a = fmaf(k0, b0, y0a);
            y0b = fmaf(k1, b1, y0b);
            y1a = fmaf(k0, c0, y1a);
            y1b = fmaf(k1, c1, y1b);
        }
    }
    float y0 = fmaxf(y0a + y0b, 0.f);
    float y1 = fmaxf(y1a + y1b, 0.f);
    xout[(size_t)n0 * 64 + lane] = f2bf(y0);
    xout[(size_t)(n0 + 1) * 64 + lane] = f2bf(y1);

    if (has_next) {
        float as_ = atts_n[lane];
        float ad_ = attd_n[lane];
        float ps0 = wred_sum(as_ * y0);
        float pd0 = wred_sum(ad_ * y0);
        float ps1 = wred_sum(as_ * y1);
        float pd1 = wred_sum(ad_ * y1);
        if (lane == 0) {
            snext[n0] = ps0; dnext[n0] = pd0;
            snext[n0 + 1] = ps1; dnext[n0 + 1] = pd1;
        }
    }
}

// ---------------- closing: z = KNclose @ x ; out = log_softmax(z) ----------------
__global__ __launch_bounds__(256) void k_close(const ushort* __restrict__ xin,
                                               const float* __restrict__ KNc,  // [40][64]
                                               float* __restrict__ out) {
    __shared__ float Kpad[40][65];
    int t = threadIdx.x;
    for (int idx = t; idx < 40 * 64; idx += 256)
        Kpad[idx >> 6][idx & 63] = KNc[idx];   // coalesced global read
    __syncthreads();

    int lane = t & 63;
    int wid = t >> 6;

    float krow[64];
    int kr = (lane < 40) ? lane : 0;
#pragma unroll
    for (int c = 0; c < 64; ++c) krow[c] = (lane < 40) ? Kpad[kr][c] : 0.f;

    int n0 = (blockIdx.x * 4 + wid) * NPW;

    float xv0 = bflo((uint)xin[(size_t)n0 * 64 + lane]);
    float xv1 = bflo((uint)xin[(size_t)(n0 + 1) * 64 + lane]);

    float z0a = 0.f, z0b = 0.f, z1a = 0.f, z1b = 0.f;
#pragma unroll
    for (int c = 0; c < 64; c += 2) {
        float k0 = krow[c], k1 = krow[c + 1];
        float b0 = bcast_lane(xv0, c), b1 = bcast_lane(xv0, c + 1);
        float c0 = bcast_lane(xv1, c), c1 = bcast_lane(xv1, c + 1);
        z0a = fmaf(k0, b0, z0a);
        z0b = fmaf(k1, b1, z0b);
        z1a = fmaf(k0, c0, z1a);
        z1b = fmaf(k1, c1, z1b);
    }
    float z0 = z0a + z0b;
    float z1 = z1a + z1b;

    float zm0 = (lane < 40) ? z0 : -1e30f;
    float zm1 = (lane < 40) ? z1 : -1e30f;
    float m0 = wred_max(zm0);
    float m1 = wred_max(zm1);
    float p0 = (lane < 40) ? __expf(z0 - m0) : 0.f;
    float p1 = (lane < 40) ? __expf(z1 - m1) : 0.f;
    float su0 = wred_sum(p0);
    float su1 = wred_sum(p1);
    if (lane < 40) {
        out[(size_t)n0 * 40 + lane] = z0 - m0 - logf(su0);
        out[(size_t)(n0 + 1) * 40 + lane] = z1 - m1 - logf(su1);
    }
}

// ---------------- host ----------------
extern "C" void kernel_launch(void* const* d_in, const int* in_sizes, int n_in,
                              void* d_out, int out_size, void* d_ws, size_t ws_size,
                              hipStream_t stream) {
    const float* xn    = (const float*)d_in[0];
    const float* K1    = (const float*)d_in[1];
    const float* KNc   = (const float*)d_in[2];
    const float* KN1   = (const float*)d_in[3];
    const float* atts  = (const float*)d_in[4];
    const float* attd  = (const float*)d_in[5];
    const float* omega = (const float*)d_in[6];
    const int*   ei    = (const int*)d_in[7];
    const int*   ej    = (const int*)d_in[8];
    float* out = (float*)d_out;

    char* ws = (char*)d_ws;
    size_t off = 0;
    auto alloc = [&](size_t b) -> void* {
        void* p = ws + off;
        off = (off + b + 255) & ~(size_t)255;
        return p;
    };
    ushort* xa    = (ushort*)alloc((size_t)NN * 64 * 2);
    ushort* xb    = (ushort*)alloc((size_t)NN * 64 * 2);
    float* sA     = (float*)alloc((size_t)NN * 4);
    float* dA     = (float*)alloc((size_t)NN * 4);
    float* sB     = (float*)alloc((size_t)NN * 4);
    float* dB     = (float*)alloc((size_t)NN * 4);
    int*   rowptr = (int*)alloc((size_t)(NN + 1) * 4);
    int*   cursor = (int*)alloc((size_t)NN * 4);
    int*   csrj   = (int*)alloc((size_t)NET * 4);
    int*   bsum   = (int*)alloc((size_t)NB_SCAN * 4);
    int*   boff   = (int*)alloc((size_t)NB_SCAN * 4);
    if (off > ws_size) return;

    // CSR build (once per call; I is fixed across layers)
    (void)hipMemsetAsync(cursor, 0, (size_t)NN * 4, stream);
    k_count<<<(NET + 255) / 256, 256, 0, stream>>>(ei, cursor);
    k_scan1<<<NB_SCAN, 1024, 0, stream>>>(cursor, rowptr, bsum);
    k_scan2<<<1, 64, 0, stream>>>(bsum, boff, rowptr);
    k_scan3<<<NB_SCAN, 1024, 0, stream>>>(rowptr, boff, cursor);
    k_fill<<<(NET + 255) / 256, 256, 0, stream>>>(ei, ej, cursor, csrj);

    // opening
    k_open<<<(NN + 63) / 64, 256, 0, stream>>>(xn, K1, atts, attd, xa, sA, dA);

    // layers (ping-pong x and s/d)
    const int LBLK = NN / (4 * NPW);           // 6250, exact
    const ushort* xi = xa; ushort* xo = xb;
    const float* si = sA; const float* di = dA;
    float* so = sB; float* dn = dB;
    for (int l = 0; l < 4; ++l) {
        int hn = (l < 3) ? 1 : 0;
        int nl = (l < 3) ? (l + 1) : 0;
        k_layer<<<LBLK, 256, 0, stream>>>(xi, xo, si, di, so, dn, rowptr, csrj,
                                          KN1 + (size_t)l * 4096, omega + l * 64,
                                          atts + (size_t)nl * 64, attd + (size_t)nl * 64, hn);
        const ushort* t0 = xi; xi = xo; xo = (ushort*)t0;
        const float* t1 = si; si = so; so = (float*)t1;
        const float* t2 = di; di = dn; dn = (float*)t2;
    }

    // closing + log_softmax
    k_close<<<LBLK, 256, 0, stream>>>(xi, KNc, out);
}

// Round 6
// 381.988 us; speedup vs baseline: 3.1705x; 1.2059x over previous
//
#include <hip/hip_runtime.h>

#define NN 50000          // nodes
#define NE 800000         // edges (without self loops)
#define NET 850000        // NE + NN self loops
#define NB_SCAN 49        // ceil(NN/1024)

typedef unsigned int uint;
typedef unsigned short ushort;

__device__ __forceinline__ float bcast_lane(float v, int l) {
    return __int_as_float(__builtin_amdgcn_readlane(__float_as_int(v), l));
}
__device__ __forceinline__ float wred_max(float v) {
#pragma unroll
    for (int off = 32; off; off >>= 1) v = fmaxf(v, __shfl_xor(v, off, 64));
    return v;
}
__device__ __forceinline__ float wred_sum(float v) {
#pragma unroll
    for (int off = 32; off; off >>= 1) v += __shfl_xor(v, off, 64);
    return v;
}
// dual interleaved reductions: two independent chains overlap their latencies
__device__ __forceinline__ void wred_max2(float& a, float& b) {
#pragma unroll
    for (int off = 32; off; off >>= 1) {
        float ta = __shfl_xor(a, off, 64);
        float tb = __shfl_xor(b, off, 64);
        a = fmaxf(a, ta);
        b = fmaxf(b, tb);
    }
}
__device__ __forceinline__ void wred_sum2(float& a, float& b) {
#pragma unroll
    for (int off = 32; off; off >>= 1) {
        float ta = __shfl_xor(a, off, 64);
        float tb = __shfl_xor(b, off, 64);
        a += ta;
        b += tb;
    }
}
__device__ __forceinline__ ushort f2bf(float f) {   // RNE
    uint u = __float_as_uint(f);
    return (ushort)((u + 0x7fffu + ((u >> 16) & 1u)) >> 16);
}
__device__ __forceinline__ float bflo(uint u) { return __uint_as_float(u << 16); }
__device__ __forceinline__ float bfhi(uint u) { return __uint_as_float(u & 0xffff0000u); }
__device__ __forceinline__ float lrelu(float a) { return (a > 0.f) ? a : 0.2f * a; }

__device__ __forceinline__ void acc8_fma(float* acc8, float wgt, uint4 v) {
    acc8[0] = fmaf(wgt, bflo(v.x), acc8[0]);
    acc8[1] = fmaf(wgt, bfhi(v.x), acc8[1]);
    acc8[2] = fmaf(wgt, bflo(v.y), acc8[2]);
    acc8[3] = fmaf(wgt, bfhi(v.y), acc8[3]);
    acc8[4] = fmaf(wgt, bflo(v.z), acc8[4]);
    acc8[5] = fmaf(wgt, bfhi(v.z), acc8[5]);
    acc8[6] = fmaf(wgt, bflo(v.w), acc8[6]);
    acc8[7] = fmaf(wgt, bfhi(v.w), acc8[7]);
}

// single-node generic fallback (deg > 64: astronomically rare)
__device__ void node_aggregate_generic(const ushort* __restrict__ xin,
                                       const float* __restrict__ darr,
                                       const int* __restrict__ csrj,
                                       int rs, int deg, float s_n,
                                       int lane, int c8, float* out8) {
    float acc8[8] = {0.f, 0.f, 0.f, 0.f, 0.f, 0.f, 0.f, 0.f};
    int re = rs + deg;
    float mxd = -1e30f;
    for (int e = rs + lane; e < re; e += 64) mxd = fmaxf(mxd, darr[csrj[e]]);
    mxd = wred_max(mxd);
    float mx = lrelu(s_n + mxd);
    float sm = 0.f;
    for (int e = rs + lane; e < re; e += 64)
        sm += __expf(lrelu(s_n + darr[csrj[e]]) - mx);
    sm = wred_sum(sm);
    float inv = 1.f / sm;
    for (int e = rs; e < re; ++e) {
        int j = csrj[e];
        float w = __expf(lrelu(s_n + darr[j]) - mx);
        uint4 v = *(const uint4*)(xin + (((size_t)j) << 6) + (c8 << 3));
        acc8_fma(acc8, w, v);
    }
#pragma unroll
    for (int q = 0; q < 8; ++q) out8[q] = acc8[q] * inv;
}

// Dual-node aggregation, fully interleaved (both nodes' chains in flight).
__device__ __forceinline__ void dual_aggregate(const ushort* __restrict__ xin,
                                               const float* __restrict__ darr,
                                               const int* __restrict__ csrj,
                                               int r0, int deg0, float sn0, int jl0, float dl0,
                                               int r1, int deg1, float sn1, int jl1, float dl1,
                                               int lane, int g, int c8,
                                               float* o0, float* o1) {
    if (deg0 <= 64 && deg1 <= 64) {
        // interleaved max chains (leaky_relu monotone: max LR(s+d_j) = LR(s+max d_j))
        float m0 = dl0, m1 = dl1;
        wred_max2(m0, m1);
        float mx0 = lrelu(sn0 + m0);
        float mx1 = lrelu(sn1 + m1);
        float w0 = (lane < deg0) ? __expf(lrelu(sn0 + dl0) - mx0) : 0.f;
        float w1 = (lane < deg1) ? __expf(lrelu(sn1 + dl1) - mx1) : 0.f;
        float su0 = w0, su1 = w1;
        wred_sum2(su0, su1);
        float inv0 = 1.f / su0, inv1 = 1.f / su1;

        float acc0[8] = {0.f, 0.f, 0.f, 0.f, 0.f, 0.f, 0.f, 0.f};
        float acc1[8] = {0.f, 0.f, 0.f, 0.f, 0.f, 0.f, 0.f, 0.f};

        // joint main loop: 4 independent uint4 gathers in flight (16 edges/node... 16+16)
        int md = min(deg0, deg1);
        int tt = 0;
        for (; tt + 16 <= md; tt += 16) {
            int e0 = tt + g, e1 = tt + 8 + g;
            int   ja = __shfl(jl0, e0); float wa = __shfl(w0, e0);
            int   jb = __shfl(jl0, e1); float wb = __shfl(w0, e1);
            int   jc = __shfl(jl1, e0); float wc = __shfl(w1, e0);
            int   jd = __shfl(jl1, e1); float wd = __shfl(w1, e1);
            uint4 va = *(const uint4*)(xin + (((size_t)ja) << 6) + (c8 << 3));
            uint4 vb = *(const uint4*)(xin + (((size_t)jb) << 6) + (c8 << 3));
            uint4 vc = *(const uint4*)(xin + (((size_t)jc) << 6) + (c8 << 3));
            uint4 vd = *(const uint4*)(xin + (((size_t)jd) << 6) + (c8 << 3));
            acc8_fma(acc0, wa, va);
            acc8_fma(acc0, wb, vb);
            acc8_fma(acc1, wc, vc);
            acc8_fma(acc1, wd, vd);
        }
        // dual 8-edge steps while both still have edges
        for (; tt + 8 <= md; tt += 8) {
            int e = tt + g;
            int   ja = __shfl(jl0, e); float wa = __shfl(w0, e);
            int   jc = __shfl(jl1, e); float wc = __shfl(w1, e);
            uint4 va = *(const uint4*)(xin + (((size_t)ja) << 6) + (c8 << 3));
            uint4 vc = *(const uint4*)(xin + (((size_t)jc) << 6) + (c8 << 3));
            acc8_fma(acc0, wa, va);
            acc8_fma(acc1, wc, vc);
        }
        // remainders (predicated 8-edge steps)
        for (int u = tt; u < deg0; u += 8) {
            int e = u + g;
            bool ok = e < deg0;
            int ec = ok ? e : 0;
            int   j = __shfl(jl0, ec);
            float w = ok ? __shfl(w0, ec) : 0.f;
            uint4 v = *(const uint4*)(xin + (((size_t)j) << 6) + (c8 << 3));
            acc8_fma(acc0, w, v);
        }
        for (int u = tt; u < deg1; u += 8) {
            int e = u + g;
            bool ok = e < deg1;
            int ec = ok ? e : 0;
            int   j = __shfl(jl1, ec);
            float w = ok ? __shfl(w1, ec) : 0.f;
            uint4 v = *(const uint4*)(xin + (((size_t)j) << 6) + (c8 << 3));
            acc8_fma(acc1, w, v);
        }
        // interleaved xor-reduce across the 8 edge groups
#pragma unroll
        for (int q = 0; q < 8; ++q) {
            float a = acc0[q], b = acc1[q];
            float ta = __shfl_xor(a, 8, 64),  tb = __shfl_xor(b, 8, 64);
            a += ta; b += tb;
            ta = __shfl_xor(a, 16, 64); tb = __shfl_xor(b, 16, 64);
            a += ta; b += tb;
            ta = __shfl_xor(a, 32, 64); tb = __shfl_xor(b, 32, 64);
            a += ta; b += tb;
            o0[q] = a * inv0;
            o1[q] = b * inv1;
        }
    } else {
        node_aggregate_generic(xin, darr, csrj, r0, deg0, sn0, lane, c8, o0);
        node_aggregate_generic(xin, darr, csrj, r1, deg1, sn1, lane, c8, o1);
    }
}

// ---------------- CSR build ----------------
__global__ void k_count(const int* __restrict__ ei, int* __restrict__ cnt) {
    int e = blockIdx.x * blockDim.x + threadIdx.x;
    if (e < NET) {
        int i = (e < NE) ? ei[e] : (e - NE);   // self loop dest
        atomicAdd(&cnt[i], 1);
    }
}

__global__ __launch_bounds__(1024) void k_scan1(const int* __restrict__ cnt,
                                                int* __restrict__ rowptr,
                                                int* __restrict__ bsum) {
    __shared__ int sh[1024];
    int t = threadIdx.x;
    int i = blockIdx.x * 1024 + t;
    int v = (i < NN) ? cnt[i] : 0;
    sh[t] = v;
    __syncthreads();
    for (int off = 1; off < 1024; off <<= 1) {
        int add = (t >= off) ? sh[t - off] : 0;
        __syncthreads();
        sh[t] += add;
        __syncthreads();
    }
    int incl = sh[t];
    if (i < NN) rowptr[i] = incl - v;          // exclusive, pre-block-offset
    if (t == 1023) bsum[blockIdx.x] = incl;
}

__global__ void k_scan2(const int* __restrict__ bsum, int* __restrict__ boff,
                        int* __restrict__ rowptr) {
    int lane = threadIdx.x;                    // 64 threads, 1 block
    int v = (lane < NB_SCAN) ? bsum[lane] : 0;
    int p = v;
#pragma unroll
    for (int off = 1; off < 64; off <<= 1) {
        int nv = __shfl_up(p, off, 64);
        if (lane >= off) p += nv;
    }
    if (lane < NB_SCAN) boff[lane] = p - v;    // exclusive
    if (lane == 63) rowptr[NN] = p;            // grand total
}

__global__ __launch_bounds__(1024) void k_scan3(int* __restrict__ rowptr,
                                                const int* __restrict__ boff,
                                                int* __restrict__ cursor) {
    int i = blockIdx.x * 1024 + threadIdx.x;
    if (i < NN) {
        int r = rowptr[i] + boff[i >> 10];
        rowptr[i] = r;
        cursor[i] = r;
    }
}

__global__ void k_fill(const int* __restrict__ ei, const int* __restrict__ ej,
                       int* __restrict__ cursor, int* __restrict__ csrj) {
    int e = blockIdx.x * blockDim.x + threadIdx.x;
    if (e < NET) {
        int i, j;
        if (e < NE) { i = ei[e]; j = ej[e]; }
        else        { i = e - NE; j = i; }
        int pos = atomicAdd(&cursor[i], 1);
        csrj[pos] = j;
    }
}

// ---------------- opening: x0[n][o] = relu(K1 @ xn) (bf16 out), plus s,d ----------------
__global__ __launch_bounds__(256) void k_open(const float* __restrict__ xn,
                                              const float* __restrict__ K1,
                                              const float* __restrict__ att_s,
                                              const float* __restrict__ att_d,
                                              ushort* __restrict__ x0,
                                              float* __restrict__ s0,
                                              float* __restrict__ d0) {
    __shared__ float xs[128][64];   // 32 KB  xs[c][local n]
    __shared__ float Kt[128][64];   // 32 KB  Kt[c][o] = K1[o][c]
    int t = threadIdx.x;
    int n0 = blockIdx.x * 64;

    for (int idx = t; idx < 128 * 64; idx += 256) {
        int c = idx >> 6, o = idx & 63;
        Kt[c][o] = K1[o * 128 + c];
    }
    for (int idx = t; idx < 128 * 64; idx += 256) {
        int c = idx >> 6, ln = idx & 63;
        int n = n0 + ln;
        xs[c][ln] = (n < NN) ? xn[(size_t)c * NN + n] : 0.f;
    }
    __syncthreads();

    int tx = t & 15;    // output quad: o = tx*4 .. tx*4+3
    int ty = t >> 4;    // node quad:   n = n0 + ty*4 .. +3

    float acc[4][4] = {};
    for (int c = 0; c < 128; ++c) {
        float4 xv = *(const float4*)&xs[c][ty * 4];
        float4 kv = *(const float4*)&Kt[c][tx * 4];
        acc[0][0] = fmaf(xv.x, kv.x, acc[0][0]); acc[0][1] = fmaf(xv.x, kv.y, acc[0][1]);
        acc[0][2] = fmaf(xv.x, kv.z, acc[0][2]); acc[0][3] = fmaf(xv.x, kv.w, acc[0][3]);
        acc[1][0] = fmaf(xv.y, kv.x, acc[1][0]); acc[1][1] = fmaf(xv.y, kv.y, acc[1][1]);
        acc[1][2] = fmaf(xv.y, kv.z, acc[1][2]); acc[1][3] = fmaf(xv.y, kv.w, acc[1][3]);
        acc[2][0] = fmaf(xv.z, kv.x, acc[2][0]); acc[2][1] = fmaf(xv.z, kv.y, acc[2][1]);
        acc[2][2] = fmaf(xv.z, kv.z, acc[2][2]); acc[2][3] = fmaf(xv.z, kv.w, acc[2][3]);
        acc[3][0] = fmaf(xv.w, kv.x, acc[3][0]); acc[3][1] = fmaf(xv.w, kv.y, acc[3][1]);
        acc[3][2] = fmaf(xv.w, kv.z, acc[3][2]); acc[3][3] = fmaf(xv.w, kv.w, acc[3][3]);
    }

    float asv[4], adv[4];
#pragma unroll
    for (int j = 0; j < 4; ++j) { asv[j] = att_s[tx * 4 + j]; adv[j] = att_d[tx * 4 + j]; }

#pragma unroll
    for (int i = 0; i < 4; ++i) {
        int n = n0 + ty * 4 + i;
        if (n >= NN) continue;                 // uniform across the 16-lane tx group
        float4 r;
        r.x = fmaxf(acc[i][0], 0.f); r.y = fmaxf(acc[i][1], 0.f);
        r.z = fmaxf(acc[i][2], 0.f); r.w = fmaxf(acc[i][3], 0.f);
        float ps = r.x * asv[0] + r.y * asv[1] + r.z * asv[2] + r.w * asv[3];
        float pd = r.x * adv[0] + r.y * adv[1] + r.z * adv[2] + r.w * adv[3];
#pragma unroll
        for (int off = 1; off < 16; off <<= 1) {
            ps += __shfl_xor(ps, off, 64);
            pd += __shfl_xor(pd, off, 64);
        }
        if (tx == 0) { s0[n] = ps; d0[n] = pd; }
        ushort4 h;
        h.x = f2bf(r.x); h.y = f2bf(r.y); h.z = f2bf(r.z); h.w = f2bf(r.w);
        *(ushort4*)&x0[(size_t)n * 64 + tx * 4] = h;
    }
}

// ---------------- fused layer ----------------
// 512-thread blocks (8 waves), 2 nodes per wave, dual-interleaved chains.
// 3125 blocks x 16 nodes = 50000 exactly.
__global__ __launch_bounds__(512, 4) void k_layer(const ushort* __restrict__ xin,
                                                  ushort* __restrict__ xout,
                                                  const float* __restrict__ sarr,
                                                  const float* __restrict__ darr,
                                                  float* __restrict__ snext,
                                                  float* __restrict__ dnext,
                                                  const int* __restrict__ rowptr,
                                                  const int* __restrict__ csrj,
                                                  const float* __restrict__ Kl,   // [64][64]
                                                  const float* __restrict__ om_l,
                                                  const float* __restrict__ atts_n,
                                                  const float* __restrict__ attd_n,
                                                  int has_next) {
    __shared__ float Kpad[64][65];             // +1 pad: conflict-free
    int t = threadIdx.x;
    for (int idx = t; idx < 64 * 64; idx += 512)
        Kpad[idx >> 6][idx & 63] = Kl[idx];    // coalesced global read
    __syncthreads();

    int lane = t & 63;
    int wid = t >> 6;                          // 0..7
    int g  = lane >> 3;   // edge subgroup 0..7
    int c8 = lane & 7;    // channel octet

    int n0 = (blockIdx.x * 8 + wid) * 2;       // exact cover, no guard needed

    // ---- prologue: both nodes' headers + edge caches + center rows ----
    int r0 = rowptr[n0], r1 = rowptr[n0 + 1], r2 = rowptr[n0 + 2];
    int deg0 = r1 - r0, deg1 = r2 - r1;
    float sn0 = sarr[n0], sn1 = sarr[n0 + 1];
    int   jl0 = (lane < deg0) ? csrj[r0 + lane] : 0;
    int   jl1 = (lane < deg1) ? csrj[r1 + lane] : 0;
    float dl0 = (lane < deg0) ? darr[jl0] : -1e30f;
    float dl1 = (lane < deg1) ? darr[jl1] : -1e30f;
    uint4 xcv0 = *(const uint4*)(xin + (((size_t)n0) << 6) + (c8 << 3));
    uint4 xcv1 = *(const uint4*)(xin + (((size_t)(n0 + 1)) << 6) + (c8 << 3));

    // ---- dual aggregation (interleaved chains) ----
    float t0a[8], t1a[8];
    dual_aggregate(xin, darr, csrj, r0, deg0, sn0, jl0, dl0,
                   r1, deg1, sn1, jl1, dl1, lane, g, c8, t0a, t1a);

    // ---- omega residual (in place) ----
    {
        float4 a = *(const float4*)&om_l[c8 * 8];
        float4 b = *(const float4*)&om_l[c8 * 8 + 4];
        float om8[8] = {a.x, a.y, a.z, a.w, b.x, b.y, b.z, b.w};
        float xc;
        xc = bflo(xcv0.x); t0a[0] = xc - om8[0] * (xc - t0a[0]);
        xc = bfhi(xcv0.x); t0a[1] = xc - om8[1] * (xc - t0a[1]);
        xc = bflo(xcv0.y); t0a[2] = xc - om8[2] * (xc - t0a[2]);
        xc = bfhi(xcv0.y); t0a[3] = xc - om8[3] * (xc - t0a[3]);
        xc = bflo(xcv0.z); t0a[4] = xc - om8[4] * (xc - t0a[4]);
        xc = bfhi(xcv0.z); t0a[5] = xc - om8[5] * (xc - t0a[5]);
        xc = bflo(xcv0.w); t0a[6] = xc - om8[6] * (xc - t0a[6]);
        xc = bfhi(xcv0.w); t0a[7] = xc - om8[7] * (xc - t0a[7]);
        xc = bflo(xcv1.x); t1a[0] = xc - om8[0] * (xc - t1a[0]);
        xc = bfhi(xcv1.x); t1a[1] = xc - om8[1] * (xc - t1a[1]);
        xc = bflo(xcv1.y); t1a[2] = xc - om8[2] * (xc - t1a[2]);
        xc = bfhi(xcv1.y); t1a[3] = xc - om8[3] * (xc - t1a[3]);
        xc = bflo(xcv1.z); t1a[4] = xc - om8[4] * (xc - t1a[4]);
        xc = bfhi(xcv1.z); t1a[5] = xc - om8[5] * (xc - t1a[5]);
        xc = bflo(xcv1.w); t1a[6] = xc - om8[6] * (xc - t1a[6]);
        xc = bfhi(xcv1.w); t1a[7] = xc - om8[7] * (xc - t1a[7]);
    }

    // ---- fused dual 64x64 GEMM: K reads shared, 4 independent FMA chains ----
    float y0a = 0.f, y0b = 0.f, y1a = 0.f, y1b = 0.f;
#pragma unroll
    for (int q = 0; q < 8; ++q) {
#pragma unroll
        for (int kk = 0; kk < 8; kk += 2) {
            float k0 = Kpad[lane][q * 8 + kk];
            float k1 = Kpad[lane][q * 8 + kk + 1];
            float b0 = bcast_lane(t0a[kk], q);
            float b1 = bcast_lane(t0a[kk + 1], q);
            float c0 = bcast_lane(t1a[kk], q);
            float c1 = bcast_lane(t1a[kk + 1], q);
            y0a = fmaf(k0, b0, y0a);
            y0b = fmaf(k1, b1, y0b);
            y1a = fmaf(k0, c0, y1a);
            y1b = fmaf(k1, c1, y1b);
        }
    }
    float y0 = fmaxf(y0a + y0b, 0.f);
    float y1 = fmaxf(y1a + y1b, 0.f);
    xout[(size_t)n0 * 64 + lane] = f2bf(y0);
    xout[(size_t)(n0 + 1) * 64 + lane] = f2bf(y1);

    if (has_next) {
        float as_ = atts_n[lane];
        float ad_ = attd_n[lane];
        float ps0 = as_ * y0, pd0 = ad_ * y0;
        float ps1 = as_ * y1, pd1 = ad_ * y1;
        wred_sum2(ps0, pd0);
        wred_sum2(ps1, pd1);
        if (lane == 0) {
            snext[n0] = ps0; dnext[n0] = pd0;
            snext[n0 + 1] = ps1; dnext[n0 + 1] = pd1;
        }
    }
}

// ---------------- closing: z = KNclose @ x ; out = log_softmax(z) ----------------
// 512-thread blocks, 4 nodes per wave as two dual-pairs.
__global__ __launch_bounds__(512) void k_close(const ushort* __restrict__ xin,
                                               const float* __restrict__ KNc,  // [40][64]
                                               float* __restrict__ out) {
    __shared__ float Kpad[40][65];
    int t = threadIdx.x;
    for (int idx = t; idx < 40 * 64; idx += 512)
        Kpad[idx >> 6][idx & 63] = KNc[idx];   // coalesced global read
    __syncthreads();

    int lane = t & 63;
    int wid = t >> 6;

    int kr = (lane < 40) ? lane : 0;
    int base = (blockIdx.x * 8 + wid) * 4;

#pragma unroll
    for (int p = 0; p < 2; ++p) {
        int n0 = base + p * 2;
        if (n0 >= NN) break;                   // wave-uniform; NN even so pairs never straddle

        float xv0 = bflo((uint)xin[(size_t)n0 * 64 + lane]);
        float xv1 = bflo((uint)xin[(size_t)(n0 + 1) * 64 + lane]);

        float z0a = 0.f, z0b = 0.f, z1a = 0.f, z1b = 0.f;
#pragma unroll
        for (int c = 0; c < 64; c += 2) {
            float k0 = (lane < 40) ? Kpad[kr][c] : 0.f;
            float k1 = (lane < 40) ? Kpad[kr][c + 1] : 0.f;
            float b0 = bcast_lane(xv0, c), b1 = bcast_lane(xv0, c + 1);
            float c0 = bcast_lane(xv1, c), c1 = bcast_lane(xv1, c + 1);
            z0a = fmaf(k0, b0, z0a);
            z0b = fmaf(k1, b1, z0b);
            z1a = fmaf(k0, c0, z1a);
            z1b = fmaf(k1, c1, z1b);
        }
        float z0 = z0a + z0b;
        float z1 = z1a + z1b;

        float zm0 = (lane < 40) ? z0 : -1e30f;
        float zm1 = (lane < 40) ? z1 : -1e30f;
        wred_max2(zm0, zm1);
        float p0 = (lane < 40) ? __expf(z0 - zm0) : 0.f;
        float p1 = (lane < 40) ? __expf(z1 - zm1) : 0.f;
        wred_sum2(p0, p1);
        if (lane < 40) {
            out[(size_t)n0 * 40 + lane] = z0 - zm0 - logf(p0);
            out[(size_t)(n0 + 1) * 40 + lane] = z1 - zm1 - logf(p1);
        }
    }
}

// ---------------- host ----------------
extern "C" void kernel_launch(void* const* d_in, const int* in_sizes, int n_in,
                              void* d_out, int out_size, void* d_ws, size_t ws_size,
                              hipStream_t stream) {
    const float* xn    = (const float*)d_in[0];
    const float* K1    = (const float*)d_in[1];
    const float* KNc   = (const float*)d_in[2];
    const float* KN1   = (const float*)d_in[3];
    const float* atts  = (const float*)d_in[4];
    const float* attd  = (const float*)d_in[5];
    const float* omega = (const float*)d_in[6];
    const int*   ei    = (const int*)d_in[7];
    const int*   ej    = (const int*)d_in[8];
    float* out = (float*)d_out;

    char* ws = (char*)d_ws;
    size_t off = 0;
    auto alloc = [&](size_t b) -> void* {
        void* p = ws + off;
        off = (off + b + 255) & ~(size_t)255;
        return p;
    };
    ushort* xa    = (ushort*)alloc((size_t)NN * 64 * 2);
    ushort* xb    = (ushort*)alloc((size_t)NN * 64 * 2);
    float* sA     = (float*)alloc((size_t)NN * 4);
    float* dA     = (float*)alloc((size_t)NN * 4);
    float* sB     = (float*)alloc((size_t)NN * 4);
    float* dB     = (float*)alloc((size_t)NN * 4);
    int*   rowptr = (int*)alloc((size_t)(NN + 1) * 4);
    int*   cursor = (int*)alloc((size_t)NN * 4);
    int*   csrj   = (int*)alloc((size_t)NET * 4);
    int*   bsum   = (int*)alloc((size_t)NB_SCAN * 4);
    int*   boff   = (int*)alloc((size_t)NB_SCAN * 4);
    if (off > ws_size) return;

    // CSR build (once per call; I is fixed across layers)
    (void)hipMemsetAsync(cursor, 0, (size_t)NN * 4, stream);
    k_count<<<(NET + 255) / 256, 256, 0, stream>>>(ei, cursor);
    k_scan1<<<NB_SCAN, 1024, 0, stream>>>(cursor, rowptr, bsum);
    k_scan2<<<1, 64, 0, stream>>>(bsum, boff, rowptr);
    k_scan3<<<NB_SCAN, 1024, 0, stream>>>(rowptr, boff, cursor);
    k_fill<<<(NET + 255) / 256, 256, 0, stream>>>(ei, ej, cursor, csrj);

    // opening
    k_open<<<(NN + 63) / 64, 256, 0, stream>>>(xn, K1, atts, attd, xa, sA, dA);

    // layers (ping-pong x and s/d)
    const int LBLK = NN / 16;                  // 3125, exact (16 nodes per 512-thr block)
    const ushort* xi = xa; ushort* xo = xb;
    const float* si = sA; const float* di = dA;
    float* so = sB; float* dn = dB;
    for (int l = 0; l < 4; ++l) {
        int hn = (l < 3) ? 1 : 0;
        int nl = (l < 3) ? (l + 1) : 0;
        k_layer<<<LBLK, 512, 0, stream>>>(xi, xo, si, di, so, dn, rowptr, csrj,
                                          KN1 + (size_t)l * 4096, omega + l * 64,
                                          atts + (size_t)nl * 64, attd + (size_t)nl * 64, hn);
        const ushort* t0 = xi; xi = xo; xo = (ushort*)t0;
        const float* t1 = si; si = so; so = (float*)t1;
        const float* t2 = di; di = dn; dn = (float*)t2;
    }

    // closing + log_softmax (32 nodes per 512-thr block)
    k_close<<<(NN + 31) / 32, 512, 0, stream>>>(xi, KNc, out);
}

// Round 7
// 339.358 us; speedup vs baseline: 3.5687x; 1.1256x over previous
//
#include <hip/hip_runtime.h>

#define NN 50000          // nodes
#define NE 800000         // edges (without self loops)
#define NET 850000        // NE + NN self loops
#define NB_SCAN 49        // ceil(NN/1024)
#define OPEN_BLOCKS 782   // ceil(NN/64)
#define EPB 1087          // ceil(NET/OPEN_BLOCKS) edges per block (fill stripe)

typedef unsigned int uint;
typedef unsigned short ushort;

__device__ __forceinline__ float bcast_lane(float v, int l) {
    return __int_as_float(__builtin_amdgcn_readlane(__float_as_int(v), l));
}
__device__ __forceinline__ float wred_max(float v) {
#pragma unroll
    for (int off = 32; off; off >>= 1) v = fmaxf(v, __shfl_xor(v, off, 64));
    return v;
}
__device__ __forceinline__ float wred_sum(float v) {
#pragma unroll
    for (int off = 32; off; off >>= 1) v += __shfl_xor(v, off, 64);
    return v;
}
// dual interleaved reductions: two independent chains overlap their latencies
__device__ __forceinline__ void wred_max2(float& a, float& b) {
#pragma unroll
    for (int off = 32; off; off >>= 1) {
        float ta = __shfl_xor(a, off, 64);
        float tb = __shfl_xor(b, off, 64);
        a = fmaxf(a, ta);
        b = fmaxf(b, tb);
    }
}
__device__ __forceinline__ void wred_sum2(float& a, float& b) {
#pragma unroll
    for (int off = 32; off; off >>= 1) {
        float ta = __shfl_xor(a, off, 64);
        float tb = __shfl_xor(b, off, 64);
        a += ta;
        b += tb;
    }
}
__device__ __forceinline__ ushort f2bf(float f) {   // RNE
    uint u = __float_as_uint(f);
    return (ushort)((u + 0x7fffu + ((u >> 16) & 1u)) >> 16);
}
__device__ __forceinline__ float bflo(uint u) { return __uint_as_float(u << 16); }
__device__ __forceinline__ float bfhi(uint u) { return __uint_as_float(u & 0xffff0000u); }
__device__ __forceinline__ float lrelu(float a) { return (a > 0.f) ? a : 0.2f * a; }

__device__ __forceinline__ void acc8_fma(float* acc8, float wgt, uint4 v) {
    acc8[0] = fmaf(wgt, bflo(v.x), acc8[0]);
    acc8[1] = fmaf(wgt, bfhi(v.x), acc8[1]);
    acc8[2] = fmaf(wgt, bflo(v.y), acc8[2]);
    acc8[3] = fmaf(wgt, bfhi(v.y), acc8[3]);
    acc8[4] = fmaf(wgt, bflo(v.z), acc8[4]);
    acc8[5] = fmaf(wgt, bfhi(v.z), acc8[5]);
    acc8[6] = fmaf(wgt, bflo(v.w), acc8[6]);
    acc8[7] = fmaf(wgt, bfhi(v.w), acc8[7]);
}

// single-node generic fallback (deg > 64: astronomically rare)
__device__ void node_aggregate_generic(const ushort* __restrict__ xin,
                                       const float* __restrict__ darr,
                                       const int* __restrict__ csrj,
                                       int rs, int deg, float s_n,
                                       int lane, int c8, float* out8) {
    float acc8[8] = {0.f, 0.f, 0.f, 0.f, 0.f, 0.f, 0.f, 0.f};
    int re = rs + deg;
    float mxd = -1e30f;
    for (int e = rs + lane; e < re; e += 64) mxd = fmaxf(mxd, darr[csrj[e]]);
    mxd = wred_max(mxd);
    float mx = lrelu(s_n + mxd);
    float sm = 0.f;
    for (int e = rs + lane; e < re; e += 64)
        sm += __expf(lrelu(s_n + darr[csrj[e]]) - mx);
    sm = wred_sum(sm);
    float inv = 1.f / sm;
    for (int e = rs; e < re; ++e) {
        int j = csrj[e];
        float w = __expf(lrelu(s_n + darr[j]) - mx);
        uint4 v = *(const uint4*)(xin + (((size_t)j) << 6) + (c8 << 3));
        acc8_fma(acc8, w, v);
    }
#pragma unroll
    for (int q = 0; q < 8; ++q) out8[q] = acc8[q] * inv;
}

// Dual-node aggregation, fully interleaved (both nodes' chains in flight).
__device__ __forceinline__ void dual_aggregate(const ushort* __restrict__ xin,
                                               const float* __restrict__ darr,
                                               const int* __restrict__ csrj,
                                               int r0, int deg0, float sn0, int jl0, float dl0,
                                               int r1, int deg1, float sn1, int jl1, float dl1,
                                               int lane, int g, int c8,
                                               float* o0, float* o1) {
    if (deg0 <= 64 && deg1 <= 64) {
        // interleaved max chains (leaky_relu monotone: max LR(s+d_j) = LR(s+max d_j))
        float m0 = dl0, m1 = dl1;
        wred_max2(m0, m1);
        float mx0 = lrelu(sn0 + m0);
        float mx1 = lrelu(sn1 + m1);
        float w0 = (lane < deg0) ? __expf(lrelu(sn0 + dl0) - mx0) : 0.f;
        float w1 = (lane < deg1) ? __expf(lrelu(sn1 + dl1) - mx1) : 0.f;
        float su0 = w0, su1 = w1;
        wred_sum2(su0, su1);
        float inv0 = 1.f / su0, inv1 = 1.f / su1;

        float acc0[8] = {0.f, 0.f, 0.f, 0.f, 0.f, 0.f, 0.f, 0.f};
        float acc1[8] = {0.f, 0.f, 0.f, 0.f, 0.f, 0.f, 0.f, 0.f};

        // joint main loop: 4 independent uint4 gathers in flight
        int md = min(deg0, deg1);
        int tt = 0;
        for (; tt + 16 <= md; tt += 16) {
            int e0 = tt + g, e1 = tt + 8 + g;
            int   ja = __shfl(jl0, e0); float wa = __shfl(w0, e0);
            int   jb = __shfl(jl0, e1); float wb = __shfl(w0, e1);
            int   jc = __shfl(jl1, e0); float wc = __shfl(w1, e0);
            int   jd = __shfl(jl1, e1); float wd = __shfl(w1, e1);
            uint4 va = *(const uint4*)(xin + (((size_t)ja) << 6) + (c8 << 3));
            uint4 vb = *(const uint4*)(xin + (((size_t)jb) << 6) + (c8 << 3));
            uint4 vc = *(const uint4*)(xin + (((size_t)jc) << 6) + (c8 << 3));
            uint4 vd = *(const uint4*)(xin + (((size_t)jd) << 6) + (c8 << 3));
            acc8_fma(acc0, wa, va);
            acc8_fma(acc0, wb, vb);
            acc8_fma(acc1, wc, vc);
            acc8_fma(acc1, wd, vd);
        }
        // dual 8-edge steps while both still have edges
        for (; tt + 8 <= md; tt += 8) {
            int e = tt + g;
            int   ja = __shfl(jl0, e); float wa = __shfl(w0, e);
            int   jc = __shfl(jl1, e); float wc = __shfl(w1, e);
            uint4 va = *(const uint4*)(xin + (((size_t)ja) << 6) + (c8 << 3));
            uint4 vc = *(const uint4*)(xin + (((size_t)jc) << 6) + (c8 << 3));
            acc8_fma(acc0, wa, va);
            acc8_fma(acc1, wc, vc);
        }
        // remainders (predicated 8-edge steps)
        for (int u = tt; u < deg0; u += 8) {
            int e = u + g;
            bool ok = e < deg0;
            int ec = ok ? e : 0;
            int   j = __shfl(jl0, ec);
            float w = ok ? __shfl(w0, ec) : 0.f;
            uint4 v = *(const uint4*)(xin + (((size_t)j) << 6) + (c8 << 3));
            acc8_fma(acc0, w, v);
        }
        for (int u = tt; u < deg1; u += 8) {
            int e = u + g;
            bool ok = e < deg1;
            int ec = ok ? e : 0;
            int   j = __shfl(jl1, ec);
            float w = ok ? __shfl(w1, ec) : 0.f;
            uint4 v = *(const uint4*)(xin + (((size_t)j) << 6) + (c8 << 3));
            acc8_fma(acc1, w, v);
        }
        // interleaved xor-reduce across the 8 edge groups
#pragma unroll
        for (int q = 0; q < 8; ++q) {
            float a = acc0[q], b = acc1[q];
            float ta = __shfl_xor(a, 8, 64),  tb = __shfl_xor(b, 8, 64);
            a += ta; b += tb;
            ta = __shfl_xor(a, 16, 64); tb = __shfl_xor(b, 16, 64);
            a += ta; b += tb;
            ta = __shfl_xor(a, 32, 64); tb = __shfl_xor(b, 32, 64);
            a += ta; b += tb;
            o0[q] = a * inv0;
            o1[q] = b * inv1;
        }
    } else {
        node_aggregate_generic(xin, darr, csrj, r0, deg0, sn0, lane, c8, o0);
        node_aggregate_generic(xin, darr, csrj, r1, deg1, sn1, lane, c8, o1);
    }
}

// ---------------- CSR build ----------------
__global__ void k_count(const int* __restrict__ ei, int* __restrict__ cnt) {
    int e = blockIdx.x * blockDim.x + threadIdx.x;
    if (e < NET) {
        int i = (e < NE) ? ei[e] : (e - NE);   // self loop dest
        atomicAdd(&cnt[i], 1);
    }
}

__global__ __launch_bounds__(1024) void k_scan1(const int* __restrict__ cnt,
                                                int* __restrict__ rowptr,
                                                int* __restrict__ bsum) {
    __shared__ int sh[1024];
    int t = threadIdx.x;
    int i = blockIdx.x * 1024 + t;
    int v = (i < NN) ? cnt[i] : 0;
    sh[t] = v;
    __syncthreads();
    for (int off = 1; off < 1024; off <<= 1) {
        int add = (t >= off) ? sh[t - off] : 0;
        __syncthreads();
        sh[t] += add;
        __syncthreads();
    }
    int incl = sh[t];
    if (i < NN) rowptr[i] = incl - v;          // exclusive, pre-block-offset
    if (t == 1023) bsum[blockIdx.x] = incl;
}

__global__ void k_scan2(const int* __restrict__ bsum, int* __restrict__ boff,
                        int* __restrict__ rowptr) {
    int lane = threadIdx.x;                    // 64 threads, 1 block
    int v = (lane < NB_SCAN) ? bsum[lane] : 0;
    int p = v;
#pragma unroll
    for (int off = 1; off < 64; off <<= 1) {
        int nv = __shfl_up(p, off, 64);
        if (lane >= off) p += nv;
    }
    if (lane < NB_SCAN) boff[lane] = p - v;    // exclusive
    if (lane == 63) rowptr[NN] = p;            // grand total
}

__global__ __launch_bounds__(1024) void k_scan3(int* __restrict__ rowptr,
                                                const int* __restrict__ boff,
                                                int* __restrict__ cursor) {
    int i = blockIdx.x * 1024 + threadIdx.x;
    if (i < NN) {
        int r = rowptr[i] + boff[i >> 10];
        rowptr[i] = r;
        cursor[i] = r;
    }
}

// ---------------- fused opening GEMM + CSR fill ----------------
// 782 blocks x 256 threads. Each block does one 64-node open tile AND one
// 1087-edge fill stripe; order alternates by block parity so resident blocks
// mix latency-bound (open) and write-BW-bound (fill) work at all times.
__device__ __forceinline__ void fill_phase(const int* __restrict__ ei,
                                           const int* __restrict__ ej,
                                           int* __restrict__ cursor,
                                           int* __restrict__ csrj,
                                           int bid, int t) {
    int base = bid * EPB;
    int end = base + EPB;
    if (end > NET) end = NET;
    for (int e = base + t; e < end; e += 256) {
        int i, j;
        if (e < NE) { i = ei[e]; j = ej[e]; }
        else        { i = e - NE; j = i; }
        int pos = atomicAdd(&cursor[i], 1);
        csrj[pos] = j;
    }
}

__global__ __launch_bounds__(256) void k_openfill(const float* __restrict__ xn,
                                                  const float* __restrict__ K1,
                                                  const float* __restrict__ att_s,
                                                  const float* __restrict__ att_d,
                                                  ushort* __restrict__ x0,
                                                  float* __restrict__ s0,
                                                  float* __restrict__ d0,
                                                  const int* __restrict__ ei,
                                                  const int* __restrict__ ej,
                                                  int* __restrict__ cursor,
                                                  int* __restrict__ csrj) {
    __shared__ float xs[64][65];   // 16.6 KB
    __shared__ float Kt[64][65];   // 16.6 KB -> 33 KB total, 4 blocks/CU
    int t = threadIdx.x;
    int bid = blockIdx.x;

    bool fill_first = (bid & 1);
    if (fill_first) fill_phase(ei, ej, cursor, csrj, bid, t);

    // ---- open phase: 64 nodes x 64 outputs, K=128 split in two 64-ch halves ----
    int n0 = bid * 64;
    int tx = t & 15;    // output quad: o = tx*4 .. +3
    int ty = t >> 4;    // node quad
    float acc[4][4] = {};

    for (int half = 0; half < 2; ++half) {
        if (half) __syncthreads();             // protect xs/Kt while others compute
        for (int idx = t; idx < 4096; idx += 256) {
            int c = idx >> 6, o = idx & 63;
            Kt[c][o] = K1[o * 128 + half * 64 + c];
        }
        if (n0 + 64 <= NN) {                   // full tile: float4 staging
            for (int idx = t; idx < 1024; idx += 256) {
                int c = idx >> 4, l4 = (idx & 15) * 4;
                float4 v = *(const float4*)&xn[(size_t)(half * 64 + c) * NN + n0 + l4];
                *(float4*)&xs[c][l4] = v;
            }
        } else {                               // last tile: guarded scalar
            for (int idx = t; idx < 4096; idx += 256) {
                int c = idx >> 6, ln = idx & 63;
                int n = n0 + ln;
                xs[c][ln] = (n < NN) ? xn[(size_t)(half * 64 + c) * NN + n] : 0.f;
            }
        }
        __syncthreads();

        for (int c = 0; c < 64; ++c) {
            float4 xv = *(const float4*)&xs[c][ty * 4];
            float4 kv = *(const float4*)&Kt[c][tx * 4];
            acc[0][0] = fmaf(xv.x, kv.x, acc[0][0]); acc[0][1] = fmaf(xv.x, kv.y, acc[0][1]);
            acc[0][2] = fmaf(xv.x, kv.z, acc[0][2]); acc[0][3] = fmaf(xv.x, kv.w, acc[0][3]);
            acc[1][0] = fmaf(xv.y, kv.x, acc[1][0]); acc[1][1] = fmaf(xv.y, kv.y, acc[1][1]);
            acc[1][2] = fmaf(xv.y, kv.z, acc[1][2]); acc[1][3] = fmaf(xv.y, kv.w, acc[1][3]);
            acc[2][0] = fmaf(xv.z, kv.x, acc[2][0]); acc[2][1] = fmaf(xv.z, kv.y, acc[2][1]);
            acc[2][2] = fmaf(xv.z, kv.z, acc[2][2]); acc[2][3] = fmaf(xv.z, kv.w, acc[2][3]);
            acc[3][0] = fmaf(xv.w, kv.x, acc[3][0]); acc[3][1] = fmaf(xv.w, kv.y, acc[3][1]);
            acc[3][2] = fmaf(xv.w, kv.z, acc[3][2]); acc[3][3] = fmaf(xv.w, kv.w, acc[3][3]);
        }
    }

    float asv[4], adv[4];
#pragma unroll
    for (int j = 0; j < 4; ++j) { asv[j] = att_s[tx * 4 + j]; adv[j] = att_d[tx * 4 + j]; }

#pragma unroll
    for (int i = 0; i < 4; ++i) {
        int n = n0 + ty * 4 + i;
        if (n < NN) {                          // uniform across the 16-lane tx group
            float4 r;
            r.x = fmaxf(acc[i][0], 0.f); r.y = fmaxf(acc[i][1], 0.f);
            r.z = fmaxf(acc[i][2], 0.f); r.w = fmaxf(acc[i][3], 0.f);
            float ps = r.x * asv[0] + r.y * asv[1] + r.z * asv[2] + r.w * asv[3];
            float pd = r.x * adv[0] + r.y * adv[1] + r.z * adv[2] + r.w * adv[3];
#pragma unroll
            for (int off = 1; off < 16; off <<= 1) {
                ps += __shfl_xor(ps, off, 64);
                pd += __shfl_xor(pd, off, 64);
            }
            if (tx == 0) { s0[n] = ps; d0[n] = pd; }
            ushort4 h;
            h.x = f2bf(r.x); h.y = f2bf(r.y); h.z = f2bf(r.z); h.w = f2bf(r.w);
            *(ushort4*)&x0[(size_t)n * 64 + tx * 4] = h;
        }
    }

    if (!fill_first) fill_phase(ei, ej, cursor, csrj, bid, t);
}

// ---------------- fused layer (+ optional close on last layer) ----------------
// 512-thread blocks (8 waves), 2 nodes per wave, dual-interleaved chains.
__global__ __launch_bounds__(512, 4) void k_layer(const ushort* __restrict__ xin,
                                                  ushort* __restrict__ xout,
                                                  const float* __restrict__ sarr,
                                                  const float* __restrict__ darr,
                                                  float* __restrict__ snext,
                                                  float* __restrict__ dnext,
                                                  const int* __restrict__ rowptr,
                                                  const int* __restrict__ csrj,
                                                  const float* __restrict__ Kl,   // [64][64]
                                                  const float* __restrict__ om_l,
                                                  const float* __restrict__ atts_n,
                                                  const float* __restrict__ attd_n,
                                                  const float* __restrict__ KNc,  // [40][64]
                                                  float* __restrict__ out,
                                                  int do_close) {
    __shared__ float Kpad[64][65];             // 16.6 KB
    __shared__ float KcPad[40][65];            // 10.4 KB (used only when do_close)
    int t = threadIdx.x;
    for (int idx = t; idx < 64 * 64; idx += 512)
        Kpad[idx >> 6][idx & 63] = Kl[idx];
    if (do_close)
        for (int idx = t; idx < 40 * 64; idx += 512)
            KcPad[idx >> 6][idx & 63] = KNc[idx];
    __syncthreads();

    int lane = t & 63;
    int wid = t >> 6;                          // 0..7
    int g  = lane >> 3;   // edge subgroup 0..7
    int c8 = lane & 7;    // channel octet

    int n0 = (blockIdx.x * 8 + wid) * 2;       // exact cover

    // ---- prologue: both nodes' headers + edge caches + center rows ----
    int r0 = rowptr[n0], r1 = rowptr[n0 + 1], r2 = rowptr[n0 + 2];
    int deg0 = r1 - r0, deg1 = r2 - r1;
    float sn0 = sarr[n0], sn1 = sarr[n0 + 1];
    int   jl0 = (lane < deg0) ? csrj[r0 + lane] : 0;
    int   jl1 = (lane < deg1) ? csrj[r1 + lane] : 0;
    float dl0 = (lane < deg0) ? darr[jl0] : -1e30f;
    float dl1 = (lane < deg1) ? darr[jl1] : -1e30f;
    uint4 xcv0 = *(const uint4*)(xin + (((size_t)n0) << 6) + (c8 << 3));
    uint4 xcv1 = *(const uint4*)(xin + (((size_t)(n0 + 1)) << 6) + (c8 << 3));

    // ---- dual aggregation (interleaved chains) ----
    float t0a[8], t1a[8];
    dual_aggregate(xin, darr, csrj, r0, deg0, sn0, jl0, dl0,
                   r1, deg1, sn1, jl1, dl1, lane, g, c8, t0a, t1a);

    // ---- omega residual (in place) ----
    {
        float4 a = *(const float4*)&om_l[c8 * 8];
        float4 b = *(const float4*)&om_l[c8 * 8 + 4];
        float om8[8] = {a.x, a.y, a.z, a.w, b.x, b.y, b.z, b.w};
        float xc;
        xc = bflo(xcv0.x); t0a[0] = xc - om8[0] * (xc - t0a[0]);
        xc = bfhi(xcv0.x); t0a[1] = xc - om8[1] * (xc - t0a[1]);
        xc = bflo(xcv0.y); t0a[2] = xc - om8[2] * (xc - t0a[2]);
        xc = bfhi(xcv0.y); t0a[3] = xc - om8[3] * (xc - t0a[3]);
        xc = bflo(xcv0.z); t0a[4] = xc - om8[4] * (xc - t0a[4]);
        xc = bfhi(xcv0.z); t0a[5] = xc - om8[5] * (xc - t0a[5]);
        xc = bflo(xcv0.w); t0a[6] = xc - om8[6] * (xc - t0a[6]);
        xc = bfhi(xcv0.w); t0a[7] = xc - om8[7] * (xc - t0a[7]);
        xc = bflo(xcv1.x); t1a[0] = xc - om8[0] * (xc - t1a[0]);
        xc = bfhi(xcv1.x); t1a[1] = xc - om8[1] * (xc - t1a[1]);
        xc = bflo(xcv1.y); t1a[2] = xc - om8[2] * (xc - t1a[2]);
        xc = bfhi(xcv1.y); t1a[3] = xc - om8[3] * (xc - t1a[3]);
        xc = bflo(xcv1.z); t1a[4] = xc - om8[4] * (xc - t1a[4]);
        xc = bfhi(xcv1.z); t1a[5] = xc - om8[5] * (xc - t1a[5]);
        xc = bflo(xcv1.w); t1a[6] = xc - om8[6] * (xc - t1a[6]);
        xc = bfhi(xcv1.w); t1a[7] = xc - om8[7] * (xc - t1a[7]);
    }

    // ---- fused dual 64x64 GEMM: K reads shared, 4 independent FMA chains ----
    float y0a = 0.f, y0b = 0.f, y1a = 0.f, y1b = 0.f;
#pragma unroll
    for (int q = 0; q < 8; ++q) {
#pragma unroll
        for (int kk = 0; kk < 8; kk += 2) {
            float k0 = Kpad[lane][q * 8 + kk];
            float k1 = Kpad[lane][q * 8 + kk + 1];
            float b0 = bcast_lane(t0a[kk], q);
            float b1 = bcast_lane(t0a[kk + 1], q);
            float c0 = bcast_lane(t1a[kk], q);
            float c1 = bcast_lane(t1a[kk + 1], q);
            y0a = fmaf(k0, b0, y0a);
            y0b = fmaf(k1, b1, y0b);
            y1a = fmaf(k0, c0, y1a);
            y1b = fmaf(k1, c1, y1b);
        }
    }
    float y0 = fmaxf(y0a + y0b, 0.f);
    float y1 = fmaxf(y1a + y1b, 0.f);

    if (!do_close) {
        xout[(size_t)n0 * 64 + lane] = f2bf(y0);
        xout[(size_t)(n0 + 1) * 64 + lane] = f2bf(y1);
        float as_ = atts_n[lane];
        float ad_ = attd_n[lane];
        float ps0 = as_ * y0, pd0 = ad_ * y0;
        float ps1 = as_ * y1, pd1 = ad_ * y1;
        wred_sum2(ps0, pd0);
        wred_sum2(ps1, pd1);
        if (lane == 0) {
            snext[n0] = ps0; dnext[n0] = pd0;
            snext[n0 + 1] = ps1; dnext[n0 + 1] = pd1;
        }
    } else {
        // close: z = KNc @ y ; out = log_softmax(z), directly from registers
        int kr = (lane < 40) ? lane : 0;
        float z0a = 0.f, z0b = 0.f, z1a = 0.f, z1b = 0.f;
#pragma unroll
        for (int c = 0; c < 64; c += 2) {
            float k0 = (lane < 40) ? KcPad[kr][c] : 0.f;
            float k1 = (lane < 40) ? KcPad[kr][c + 1] : 0.f;
            float b0 = bcast_lane(y0, c), b1 = bcast_lane(y0, c + 1);
            float c0 = bcast_lane(y1, c), c1 = bcast_lane(y1, c + 1);
            z0a = fmaf(k0, b0, z0a);
            z0b = fmaf(k1, b1, z0b);
            z1a = fmaf(k0, c0, z1a);
            z1b = fmaf(k1, c1, z1b);
        }
        float z0 = z0a + z0b;
        float z1 = z1a + z1b;
        float zm0 = (lane < 40) ? z0 : -1e30f;
        float zm1 = (lane < 40) ? z1 : -1e30f;
        wred_max2(zm0, zm1);
        float p0 = (lane < 40) ? __expf(z0 - zm0) : 0.f;
        float p1 = (lane < 40) ? __expf(z1 - zm1) : 0.f;
        wred_sum2(p0, p1);
        if (lane < 40) {
            out[(size_t)n0 * 40 + lane] = z0 - zm0 - logf(p0);
            out[(size_t)(n0 + 1) * 40 + lane] = z1 - zm1 - logf(p1);
        }
    }
}

// ---------------- host ----------------
extern "C" void kernel_launch(void* const* d_in, const int* in_sizes, int n_in,
                              void* d_out, int out_size, void* d_ws, size_t ws_size,
                              hipStream_t stream) {
    const float* xn    = (const float*)d_in[0];
    const float* K1    = (const float*)d_in[1];
    const float* KNc   = (const float*)d_in[2];
    const float* KN1   = (const float*)d_in[3];
    const float* atts  = (const float*)d_in[4];
    const float* attd  = (const float*)d_in[5];
    const float* omega = (const float*)d_in[6];
    const int*   ei    = (const int*)d_in[7];
    const int*   ej    = (const int*)d_in[8];
    float* out = (float*)d_out;

    char* ws = (char*)d_ws;
    size_t off = 0;
    auto alloc = [&](size_t b) -> void* {
        void* p = ws + off;
        off = (off + b + 255) & ~(size_t)255;
        return p;
    };
    ushort* xa    = (ushort*)alloc((size_t)NN * 64 * 2);
    ushort* xb    = (ushort*)alloc((size_t)NN * 64 * 2);
    float* sA     = (float*)alloc((size_t)NN * 4);
    float* dA     = (float*)alloc((size_t)NN * 4);
    float* sB     = (float*)alloc((size_t)NN * 4);
    float* dB     = (float*)alloc((size_t)NN * 4);
    int*   rowptr = (int*)alloc((size_t)(NN + 1) * 4);
    int*   cursor = (int*)alloc((size_t)NN * 4);
    int*   csrj   = (int*)alloc((size_t)NET * 4);
    int*   bsum   = (int*)alloc((size_t)NB_SCAN * 4);
    int*   boff   = (int*)alloc((size_t)NB_SCAN * 4);
    if (off > ws_size) return;

    // CSR count + scan (fill is fused with the opening GEMM)
    (void)hipMemsetAsync(cursor, 0, (size_t)NN * 4, stream);
    k_count<<<(NET + 255) / 256, 256, 0, stream>>>(ei, cursor);
    k_scan1<<<NB_SCAN, 1024, 0, stream>>>(cursor, rowptr, bsum);
    k_scan2<<<1, 64, 0, stream>>>(bsum, boff, rowptr);
    k_scan3<<<NB_SCAN, 1024, 0, stream>>>(rowptr, boff, cursor);

    // fused opening GEMM + CSR fill (independent workloads, overlapped)
    k_openfill<<<OPEN_BLOCKS, 256, 0, stream>>>(xn, K1, atts, attd, xa, sA, dA,
                                                ei, ej, cursor, csrj);

    // layers (ping-pong x and s/d); last layer fuses the close+log_softmax
    const int LBLK = NN / 16;                  // 3125, exact (16 nodes per 512-thr block)
    const ushort* xi = xa; ushort* xo = xb;
    const float* si = sA; const float* di = dA;
    float* so = sB; float* dn = dB;
    for (int l = 0; l < 4; ++l) {
        int close = (l == 3) ? 1 : 0;
        int nl = (l < 3) ? (l + 1) : 0;
        k_layer<<<LBLK, 512, 0, stream>>>(xi, xo, si, di, so, dn, rowptr, csrj,
                                          KN1 + (size_t)l * 4096, omega + l * 64,
                                          atts + (size_t)nl * 64, attd + (size_t)nl * 64,
                                          KNc, out, close);
        const ushort* t0 = xi; xi = xo; xo = (ushort*)t0;
        const float* t1 = si; si = so; so = (float*)t1;
        const float* t2 = di; di = dn; dn = (float*)t2;
    }
}